// Round 11
// baseline (107.523 us; speedup 1.0000x reference)
//
#include <hip/hip_runtime.h>

typedef __attribute__((ext_vector_type(8))) short short8;
typedef __attribute__((ext_vector_type(4))) float f32x4;
typedef __attribute__((ext_vector_type(16))) float f32x16;

#define B_ 8
#define T_ 128
#define N_ 170
#define F_ 64
#define ROWSTRIDE (N_ * F_) /* 10880 */

union U4 { unsigned u[4]; short8 s; };

__device__ __forceinline__ unsigned short f2bf(float f) {
    union { float f; unsigned u; } v; v.f = f;
    unsigned r = v.u + 0x7fffu + ((v.u >> 16) & 1u);
    return (unsigned short)(r >> 16);
}
__device__ __forceinline__ unsigned cvtpk(float lo, float hi) {
    unsigned d;
    asm("v_cvt_pk_bf16_f32 %0, %1, %2" : "=v"(d) : "v"(lo), "v"(hi));
    return d;
}
__device__ __forceinline__ int swz128(int row, int byteInRow) {
    return row * 128 + (byteInRow ^ ((row & 7) << 4));
}
__device__ __forceinline__ int swz256(int row, int byteInRow) {
    return row * 256 + (byteInRow ^ ((row & 15) << 4));
}
__device__ __forceinline__ short8 ldfrag16(const char* base, int row0, int kbyte, int lane) {
    int row = row0 + (lane & 15);
    return *(const short8*)(base + swz128(row, kbyte + ((lane >> 4) << 4)));
}
__device__ __forceinline__ short8 ldfrag16w(const char* base, int row0, int kbyte, int lane) {
    int row = row0 + (lane & 15);
    return *(const short8*)(base + swz256(row, kbyte + ((lane >> 4) << 4)));
}
__device__ __forceinline__ short8 ldfrag32(const char* base, int row0, int colbyte, int lane) {
    int row = row0 + (lane & 31);
    return *(const short8*)(base + swz128(row, colbyte + ((lane >> 5) << 4)));
}
__device__ __forceinline__ short8 wfragT(const unsigned short* __restrict__ wT, int nt, int kc, int lane) {
    int j  = nt * 16 + (lane & 15);
    int k0 = kc * 32 + ((lane >> 4) & 3) * 8;
    return *(const short8*)(wT + j * 64 + k0);
}
__device__ __forceinline__ f32x4 zero4() {
    f32x4 v = {0.f, 0.f, 0.f, 0.f};
    return v;
}
__device__ __forceinline__ f32x16 zero16() {
    f32x16 v = {0.f, 0.f, 0.f, 0.f, 0.f, 0.f, 0.f, 0.f,
                0.f, 0.f, 0.f, 0.f, 0.f, 0.f, 0.f, 0.f};
    return v;
}

// LayerNorm in swapped layout: lane (g,lam) holds feats nt*16+g*4+r of token lam
__device__ __forceinline__ void lnS(float (&z)[2][4][4]) {
#pragma unroll
    for (int mi = 0; mi < 2; ++mi) {
        float s = 0.f;
#pragma unroll
        for (int nt = 0; nt < 4; ++nt)
#pragma unroll
        for (int r = 0; r < 4; ++r) s += z[mi][nt][r];
        s += __shfl_xor(s, 16); s += __shfl_xor(s, 32);
        float mean = s * 0.015625f;
        float q = 0.f;
#pragma unroll
        for (int nt = 0; nt < 4; ++nt)
#pragma unroll
        for (int r = 0; r < 4; ++r) { z[mi][nt][r] -= mean; q += z[mi][nt][r] * z[mi][nt][r]; }
        q += __shfl_xor(q, 16); q += __shfl_xor(q, 32);
        float rstd = __builtin_amdgcn_rsqf(q * 0.015625f + 1e-5f);
#pragma unroll
        for (int nt = 0; nt < 4; ++nt)
#pragma unroll
        for (int r = 0; r < 4; ++r) z[mi][nt][r] *= rstd;
    }
}

// prologue: ws[w][j][k] = bf16(W_w[k][j]) — transposed k-major bf16 weights
__global__ void prep_weights(const float* __restrict__ Wq, const float* __restrict__ Wk,
                             const float* __restrict__ Wv, const float* __restrict__ Wo,
                             const float* __restrict__ Wf1, const float* __restrict__ Wf2,
                             unsigned short* __restrict__ ws) {
    const float* Ws[6] = {Wq, Wk, Wv, Wo, Wf1, Wf2};
    const float* W = Ws[blockIdx.x];
    unsigned short* o = ws + blockIdx.x * 4096;
#pragma unroll
    for (int i = 0; i < 16; ++i) {
        int idx = i * 256 + threadIdx.x;
        int j = idx >> 6, k = idx & 63;
        o[idx] = f2bf(W[k * 64 + j]);
    }
}

__global__ __launch_bounds__(256)
__attribute__((amdgpu_waves_per_eu(5, 5)))
void ta_fused(const float* __restrict__ x, const float* __restrict__ te,
              const unsigned short* __restrict__ wT,
              const float* __restrict__ bq, const float* __restrict__ bk,
              const float* __restrict__ bv, const float* __restrict__ bo,
              const float* __restrict__ bf1, const float* __restrict__ bf2,
              float* __restrict__ out)
{
    // 32 KB total: 5 blocks/CU (VGPR pinned to ~102 by waves_per_eu(5,5))
    __shared__ __align__(16) char sKb[16384];   // Q-bounce (own rows) -> K [128][64] -> O/val/h1 bounce (own rows)
    __shared__ __align__(16) char sVt[16384];   // V^T [64][128] swz256

    const int tid  = threadIdx.x;
    const int lane = tid & 63;
    const int wv   = tid >> 6;
    const int lam  = lane & 15;
    const int g    = (lane >> 4) & 3;
    const int bid  = blockIdx.x;
    const int b    = bid / N_;
    const int n    = bid - b * N_;
    const long long base = ((long long)b * T_ * N_ + n) * F_;
    const int t0w = wv * 32;

    // ---------------- P0: X = x + te straight into fragments ----------------
    short8 ax[2][2];
#pragma unroll
    for (int mi = 0; mi < 2; ++mi) {
        const float* xr = x  + base + (long long)(t0w + mi * 16 + lam) * ROWSTRIDE;
        const float* tr = te + base + (long long)(t0w + mi * 16 + lam) * ROWSTRIDE;
#pragma unroll
        for (int kc = 0; kc < 2; ++kc) {
            int f0 = kc * 32 + g * 8;
            float4 a0 = *(const float4*)(xr + f0);
            float4 a1 = *(const float4*)(xr + f0 + 4);
            float4 c0 = *(const float4*)(tr + f0);
            float4 c1 = *(const float4*)(tr + f0 + 4);
            U4 u;
            u.u[0] = cvtpk(a0.x + c0.x, a0.y + c0.y);
            u.u[1] = cvtpk(a0.z + c0.z, a0.w + c0.w);
            u.u[2] = cvtpk(a1.x + c1.x, a1.y + c1.y);
            u.u[3] = cvtpk(a1.z + c1.z, a1.w + c1.w);
            ax[mi][kc] = u.s;
        }
    }

    short8 qf[4];   // per-head Q B-fragments, live through P2 (16 VGPRs)

    // ---------------- P1: Q (bounce in own K rows) -> K (overwrite) -> V ----------------
    {
        // --- Q, swapped orientation D[j][t] ---
        {
            const unsigned short* wTp = wT;
            short8 bw[4][2]; float4 bj[4];
#pragma unroll
            for (int nt = 0; nt < 4; ++nt) {
                bw[nt][0] = wfragT(wTp, nt, 0, lane);
                bw[nt][1] = wfragT(wTp, nt, 1, lane);
                bj[nt]    = *(const float4*)(bq + nt * 16 + g * 4);
            }
            f32x4 acc[2][4];
#pragma unroll
            for (int mi = 0; mi < 2; ++mi)
#pragma unroll
            for (int nt = 0; nt < 4; ++nt) acc[mi][nt] = zero4();
#pragma unroll
            for (int kc = 0; kc < 2; ++kc)
#pragma unroll
            for (int mi = 0; mi < 2; ++mi)
#pragma unroll
            for (int nt = 0; nt < 4; ++nt)
                acc[mi][nt] = __builtin_amdgcn_mfma_f32_16x16x32_bf16(bw[nt][kc], ax[mi][kc], acc[mi][nt], 0, 0, 0);
#pragma unroll
            for (int mi = 0; mi < 2; ++mi)
#pragma unroll
            for (int nt = 0; nt < 4; ++nt) {
                unsigned d0 = cvtpk(acc[mi][nt][0] + bj[nt].x, acc[mi][nt][1] + bj[nt].y);
                unsigned d1 = cvtpk(acc[mi][nt][2] + bj[nt].z, acc[mi][nt][3] + bj[nt].w);
                unsigned long long pk = (unsigned long long)d0 | ((unsigned long long)d1 << 32);
                *(unsigned long long*)(sKb + swz128(t0w + mi * 16 + lam, (nt * 16 + g * 4) * 2)) = pk;
            }
            // read back Q as per-head B-fragments (wave-private rows; program order)
#pragma unroll
            for (int h = 0; h < 4; ++h) qf[h] = ldfrag32(sKb, t0w, h * 32, lane);
        }
        // --- K, swapped orientation, overwrites the Q bounce (own rows) ---
        {
            const unsigned short* wTp = wT + 4096;
            short8 bw[4][2]; float4 bj[4];
#pragma unroll
            for (int nt = 0; nt < 4; ++nt) {
                bw[nt][0] = wfragT(wTp, nt, 0, lane);
                bw[nt][1] = wfragT(wTp, nt, 1, lane);
                bj[nt]    = *(const float4*)(bk + nt * 16 + g * 4);
            }
            f32x4 acc[2][4];
#pragma unroll
            for (int mi = 0; mi < 2; ++mi)
#pragma unroll
            for (int nt = 0; nt < 4; ++nt) acc[mi][nt] = zero4();
#pragma unroll
            for (int kc = 0; kc < 2; ++kc)
#pragma unroll
            for (int mi = 0; mi < 2; ++mi)
#pragma unroll
            for (int nt = 0; nt < 4; ++nt)
                acc[mi][nt] = __builtin_amdgcn_mfma_f32_16x16x32_bf16(bw[nt][kc], ax[mi][kc], acc[mi][nt], 0, 0, 0);
#pragma unroll
            for (int mi = 0; mi < 2; ++mi)
#pragma unroll
            for (int nt = 0; nt < 4; ++nt) {
                unsigned d0 = cvtpk(acc[mi][nt][0] + bj[nt].x, acc[mi][nt][1] + bj[nt].y);
                unsigned d1 = cvtpk(acc[mi][nt][2] + bj[nt].z, acc[mi][nt][3] + bj[nt].w);
                unsigned long long pk = (unsigned long long)d0 | ((unsigned long long)d1 << 32);
                *(unsigned long long*)(sKb + swz128(t0w + mi * 16 + lam, (nt * 16 + g * 4) * 2)) = pk;
            }
        }
        // --- V, normal orientation -> V^T ---
        {
            const unsigned short* wTp = wT + 2 * 4096;
            short8 bw[4][2]; float bias[4];
#pragma unroll
            for (int nt = 0; nt < 4; ++nt) {
                bw[nt][0] = wfragT(wTp, nt, 0, lane);
                bw[nt][1] = wfragT(wTp, nt, 1, lane);
                bias[nt]  = bv[nt * 16 + lam];
            }
            f32x4 acc[2][4];
#pragma unroll
            for (int mi = 0; mi < 2; ++mi)
#pragma unroll
            for (int nt = 0; nt < 4; ++nt) acc[mi][nt] = zero4();
#pragma unroll
            for (int kc = 0; kc < 2; ++kc)
#pragma unroll
            for (int mi = 0; mi < 2; ++mi)
#pragma unroll
            for (int nt = 0; nt < 4; ++nt)
                acc[mi][nt] = __builtin_amdgcn_mfma_f32_16x16x32_bf16(ax[mi][kc], bw[nt][kc], acc[mi][nt], 0, 0, 0);
#pragma unroll
            for (int mi = 0; mi < 2; ++mi)
#pragma unroll
            for (int nt = 0; nt < 4; ++nt) {
                int f   = nt * 16 + lam;
                int tb0 = t0w + mi * 16 + g * 4;
                unsigned d0 = cvtpk(acc[mi][nt][0] + bias[nt], acc[mi][nt][1] + bias[nt]);
                unsigned d1 = cvtpk(acc[mi][nt][2] + bias[nt], acc[mi][nt][3] + bias[nt]);
                unsigned long long pkv = (unsigned long long)d0 | ((unsigned long long)d1 << 32);
                *(unsigned long long*)(sVt + swz256(f, tb0 * 2)) = pkv;
            }
        }
    }
    __syncthreads();   // barrier 1: K and V^T valid for all waves

    // ---------------- P2: attention, single-pass no-max softmax (scores provably < overflow) ----------------
    f32x4 oaccT[4][2];
    {
        const int tcol = lane & 31;
        const int hi4  = (lane >> 5) * 4;
#pragma unroll
        for (int h = 0; h < 4; ++h) {
            float sum = 0.f;
            f32x4 o0 = zero4(), o1 = zero4();
#pragma unroll
            for (int sb = 0; sb < 4; ++sb) {
                if (sb > wv) continue;       // causal: s-tiles 0..wv (wave-uniform)
                short8 kf = ldfrag32(sKb, sb * 32, h * 32, lane);
                __builtin_amdgcn_s_setprio(1);
                f32x16 s = __builtin_amdgcn_mfma_f32_32x32x16_bf16(kf, qf[h], zero16(), 0, 0, 0);
                __builtin_amdgcn_s_setprio(0);
                if (sb == wv) {              // diagonal tile mask
#pragma unroll
                    for (int r = 0; r < 16; ++r) {
                        int srow = (r & 3) + 8 * (r >> 2) + hi4;
                        if (srow > tcol) s[r] = -3.0e38f;
                    }
                }
                float ps[16];
#pragma unroll
                for (int r = 0; r < 16; ++r) ps[r] = __expf(s[r] * 0.25f);  // no-max: exp(s/sqrt(D))
                // pairwise sum tree (4 dep levels)
                {
                    float a0 = ps[0] + ps[1],  a1 = ps[2] + ps[3];
                    float a2 = ps[4] + ps[5],  a3 = ps[6] + ps[7];
                    float a4 = ps[8] + ps[9],  a5 = ps[10] + ps[11];
                    float a6 = ps[12] + ps[13], a7 = ps[14] + ps[15];
                    sum += ((a0 + a1) + (a2 + a3)) + ((a4 + a5) + (a6 + a7));
                }
                unsigned a0 = cvtpk(ps[0],  ps[1]);
                unsigned a1 = cvtpk(ps[4],  ps[5]);
                unsigned a2 = cvtpk(ps[8],  ps[9]);
                unsigned a3 = cvtpk(ps[12], ps[13]);
                unsigned b0 = cvtpk(ps[2],  ps[3]);
                unsigned b1 = cvtpk(ps[6],  ps[7]);
                unsigned b2 = cvtpk(ps[10], ps[11]);
                unsigned b3 = cvtpk(ps[14], ps[15]);
                asm("v_permlane32_swap_b32 %0, %1" : "+v"(a0), "+v"(a2));
                asm("v_permlane32_swap_b32 %0, %1" : "+v"(a1), "+v"(a3));
                asm("v_permlane16_swap_b32 %0, %1" : "+v"(a0), "+v"(a1));
                asm("v_permlane16_swap_b32 %0, %1" : "+v"(a2), "+v"(a3));
                asm("v_permlane32_swap_b32 %0, %1" : "+v"(b0), "+v"(b2));
                asm("v_permlane32_swap_b32 %0, %1" : "+v"(b1), "+v"(b3));
                asm("v_permlane16_swap_b32 %0, %1" : "+v"(b0), "+v"(b1));
                asm("v_permlane16_swap_b32 %0, %1" : "+v"(b2), "+v"(b3));
                U4 F0, F1;
                F0.u[0] = a0; F0.u[1] = b0; F0.u[2] = a2; F0.u[3] = b2; // t-local 0..15
                F1.u[0] = a1; F1.u[1] = b1; F1.u[2] = a3; F1.u[3] = b3; // t-local 16..31
                short8 vf = ldfrag16w(sVt, h * 16, sb * 64, lane);
                __builtin_amdgcn_s_setprio(1);
                o0 = __builtin_amdgcn_mfma_f32_16x16x32_bf16(vf, F0.s, o0, 0, 0, 0);
                o1 = __builtin_amdgcn_mfma_f32_16x16x32_bf16(vf, F1.s, o1, 0, 0, 0);
                __builtin_amdgcn_s_setprio(0);
            }
            sum += __shfl_xor(sum, 32);
            float rs = __builtin_amdgcn_rcpf(sum);
            // align rs to MFMA output columns: token = lam (F0) / lam+16 (F1)
            float rs0 = __shfl(rs, lam);
            float rs1 = __shfl(rs, lam + 16);
#pragma unroll
            for (int r = 0; r < 4; ++r) {
                oaccT[h][0][r] = o0[r] * rs0;
                oaccT[h][1][r] = o1[r] * rs1;
            }
        }
    }
    __syncthreads();   // barrier 2: all waves done reading K/V; sKb own rows reusable

    // O -> bounce in own K rows (wave-private from here on)
#pragma unroll
    for (int h = 0; h < 4; ++h)
#pragma unroll
    for (int mi = 0; mi < 2; ++mi) {
        unsigned d0 = cvtpk(oaccT[h][mi][0], oaccT[h][mi][1]);
        unsigned d1 = cvtpk(oaccT[h][mi][2], oaccT[h][mi][3]);
        unsigned long long pk = (unsigned long long)d0 | ((unsigned long long)d1 << 32);
        *(unsigned long long*)(sKb + swz128(t0w + mi * 16 + lam, (h * 16 + g * 4) * 2)) = pk;
    }

    // ---------------- P3: Wo + residual (x/te re-read) + LN ----------------
    float val[2][4][4];
    {
        short8 af[2][2];
#pragma unroll
        for (int mi = 0; mi < 2; ++mi)
#pragma unroll
        for (int kc = 0; kc < 2; ++kc) af[mi][kc] = ldfrag16(sKb, t0w + mi * 16, kc * 64, lane);
        const unsigned short* wTp = wT + 3 * 4096;
        short8 bwf[4][2]; float4 bj[4];
#pragma unroll
        for (int nt = 0; nt < 4; ++nt) {
            bwf[nt][0] = wfragT(wTp, nt, 0, lane);
            bwf[nt][1] = wfragT(wTp, nt, 1, lane);
            bj[nt]     = *(const float4*)(bo + nt * 16 + g * 4);
        }
        f32x4 acc[2][4];
#pragma unroll
        for (int mi = 0; mi < 2; ++mi)
#pragma unroll
        for (int nt = 0; nt < 4; ++nt) acc[mi][nt] = zero4();
#pragma unroll
        for (int kc = 0; kc < 2; ++kc)
#pragma unroll
        for (int mi = 0; mi < 2; ++mi)
#pragma unroll
        for (int nt = 0; nt < 4; ++nt)
            acc[mi][nt] = __builtin_amdgcn_mfma_f32_16x16x32_bf16(bwf[nt][kc], af[mi][kc], acc[mi][nt], 0, 0, 0);
#pragma unroll
        for (int mi = 0; mi < 2; ++mi)
#pragma unroll
        for (int nt = 0; nt < 4; ++nt) {
            long long roff = base + (long long)(t0w + mi * 16 + lam) * ROWSTRIDE + nt * 16 + g * 4;
            float4 xv = *(const float4*)(x + roff);
            float4 tv = *(const float4*)(te + roff);
            val[mi][nt][0] = acc[mi][nt][0] + bj[nt].x + xv.x + tv.x;
            val[mi][nt][1] = acc[mi][nt][1] + bj[nt].y + xv.y + tv.y;
            val[mi][nt][2] = acc[mi][nt][2] + bj[nt].z + xv.z + tv.z;
            val[mi][nt][3] = acc[mi][nt][3] + bj[nt].w + xv.w + tv.w;
        }
        lnS(val);
#pragma unroll
        for (int mi = 0; mi < 2; ++mi)
#pragma unroll
        for (int nt = 0; nt < 4; ++nt) {
            unsigned d0 = cvtpk(val[mi][nt][0], val[mi][nt][1]);
            unsigned d1 = cvtpk(val[mi][nt][2], val[mi][nt][3]);
            unsigned long long pk = (unsigned long long)d0 | ((unsigned long long)d1 << 32);
            *(unsigned long long*)(sKb + swz128(t0w + mi * 16 + lam, (nt * 16 + g * 4) * 2)) = pk;
        }
    }

    // ---------------- P4: FF1 + ReLU ----------------
    {
        short8 af[2][2];
#pragma unroll
        for (int mi = 0; mi < 2; ++mi)
#pragma unroll
        for (int kc = 0; kc < 2; ++kc) af[mi][kc] = ldfrag16(sKb, t0w + mi * 16, kc * 64, lane);
        const unsigned short* wTp = wT + 4 * 4096;
        short8 bwf[4][2]; float4 bj[4];
#pragma unroll
        for (int nt = 0; nt < 4; ++nt) {
            bwf[nt][0] = wfragT(wTp, nt, 0, lane);
            bwf[nt][1] = wfragT(wTp, nt, 1, lane);
            bj[nt]     = *(const float4*)(bf1 + nt * 16 + g * 4);
        }
        f32x4 acc[2][4];
#pragma unroll
        for (int mi = 0; mi < 2; ++mi)
#pragma unroll
        for (int nt = 0; nt < 4; ++nt) acc[mi][nt] = zero4();
#pragma unroll
        for (int kc = 0; kc < 2; ++kc)
#pragma unroll
        for (int mi = 0; mi < 2; ++mi)
#pragma unroll
        for (int nt = 0; nt < 4; ++nt)
            acc[mi][nt] = __builtin_amdgcn_mfma_f32_16x16x32_bf16(bwf[nt][kc], af[mi][kc], acc[mi][nt], 0, 0, 0);
#pragma unroll
        for (int mi = 0; mi < 2; ++mi)
#pragma unroll
        for (int nt = 0; nt < 4; ++nt) {
            unsigned d0 = cvtpk(fmaxf(acc[mi][nt][0] + bj[nt].x, 0.f), fmaxf(acc[mi][nt][1] + bj[nt].y, 0.f));
            unsigned d1 = cvtpk(fmaxf(acc[mi][nt][2] + bj[nt].z, 0.f), fmaxf(acc[mi][nt][3] + bj[nt].w, 0.f));
            unsigned long long pk = (unsigned long long)d0 | ((unsigned long long)d1 << 32);
            *(unsigned long long*)(sKb + swz128(t0w + mi * 16 + lam, (nt * 16 + g * 4) * 2)) = pk;
        }
    }

    // ---------------- P5: FF2 + residual + LN + float4 store ----------------
    {
        short8 af[2][2];
#pragma unroll
        for (int mi = 0; mi < 2; ++mi)
#pragma unroll
        for (int kc = 0; kc < 2; ++kc) af[mi][kc] = ldfrag16(sKb, t0w + mi * 16, kc * 64, lane);
        const unsigned short* wTp = wT + 5 * 4096;
        short8 bwf[4][2]; float4 bj[4];
#pragma unroll
        for (int nt = 0; nt < 4; ++nt) {
            bwf[nt][0] = wfragT(wTp, nt, 0, lane);
            bwf[nt][1] = wfragT(wTp, nt, 1, lane);
            bj[nt]     = *(const float4*)(bf2 + nt * 16 + g * 4);
        }
        f32x4 acc[2][4];
#pragma unroll
        for (int mi = 0; mi < 2; ++mi)
#pragma unroll
        for (int nt = 0; nt < 4; ++nt) acc[mi][nt] = zero4();
#pragma unroll
        for (int kc = 0; kc < 2; ++kc)
#pragma unroll
        for (int mi = 0; mi < 2; ++mi)
#pragma unroll
        for (int nt = 0; nt < 4; ++nt)
            acc[mi][nt] = __builtin_amdgcn_mfma_f32_16x16x32_bf16(bwf[nt][kc], af[mi][kc], acc[mi][nt], 0, 0, 0);
        float z[2][4][4];
#pragma unroll
        for (int mi = 0; mi < 2; ++mi)
#pragma unroll
        for (int nt = 0; nt < 4; ++nt) {
            z[mi][nt][0] = acc[mi][nt][0] + bj[nt].x + val[mi][nt][0];
            z[mi][nt][1] = acc[mi][nt][1] + bj[nt].y + val[mi][nt][1];
            z[mi][nt][2] = acc[mi][nt][2] + bj[nt].z + val[mi][nt][2];
            z[mi][nt][3] = acc[mi][nt][3] + bj[nt].w + val[mi][nt][3];
        }
        lnS(z);
#pragma unroll
        for (int mi = 0; mi < 2; ++mi)
#pragma unroll
        for (int nt = 0; nt < 4; ++nt) {
            float4 o = {z[mi][nt][0], z[mi][nt][1], z[mi][nt][2], z[mi][nt][3]};
            *(float4*)(out + base + (long long)(t0w + mi * 16 + lam) * ROWSTRIDE + nt * 16 + g * 4) = o;
        }
    }
}

extern "C" void kernel_launch(void* const* d_in, const int* in_sizes, int n_in,
                              void* d_out, int out_size, void* d_ws, size_t ws_size,
                              hipStream_t stream) {
    const float* x   = (const float*)d_in[0];
    const float* te  = (const float*)d_in[1];
    const float* Wq  = (const float*)d_in[2];
    const float* bq  = (const float*)d_in[3];
    const float* Wk  = (const float*)d_in[4];
    const float* bk  = (const float*)d_in[5];
    const float* Wv  = (const float*)d_in[6];
    const float* bv  = (const float*)d_in[7];
    const float* Wo  = (const float*)d_in[8];
    const float* bo  = (const float*)d_in[9];
    const float* Wf1 = (const float*)d_in[10];
    const float* bf1 = (const float*)d_in[11];
    const float* Wf2 = (const float*)d_in[12];
    const float* bf2 = (const float*)d_in[13];
    unsigned short* wsT = (unsigned short*)d_ws;

    prep_weights<<<dim3(6), dim3(256), 0, stream>>>(Wq, Wk, Wv, Wo, Wf1, Wf2, wsT);
    ta_fused<<<dim3(B_ * N_), dim3(256), 0, stream>>>(
        x, te, wsT, bq, bk, bv, bo, bf1, bf2, (float*)d_out);
}

// Round 12
// 80.788 us; speedup vs baseline: 1.3309x; 1.3309x over previous
//
#include <hip/hip_runtime.h>

typedef __attribute__((ext_vector_type(8))) short short8;
typedef __attribute__((ext_vector_type(4))) float f32x4;
typedef __attribute__((ext_vector_type(16))) float f32x16;

#define B_ 8
#define T_ 128
#define N_ 170
#define F_ 64
#define ROWSTRIDE (N_ * F_) /* 10880 */

union U4 { unsigned u[4]; short8 s; };

__device__ __forceinline__ unsigned short f2bf(float f) {
    union { float f; unsigned u; } v; v.f = f;
    unsigned r = v.u + 0x7fffu + ((v.u >> 16) & 1u);
    return (unsigned short)(r >> 16);
}
__device__ __forceinline__ unsigned cvtpk(float lo, float hi) {
    unsigned d;
    asm("v_cvt_pk_bf16_f32 %0, %1, %2" : "=v"(d) : "v"(lo), "v"(hi));
    return d;
}
__device__ __forceinline__ int swz128(int row, int byteInRow) {
    return row * 128 + (byteInRow ^ ((row & 7) << 4));
}
__device__ __forceinline__ int swz256(int row, int byteInRow) {
    return row * 256 + (byteInRow ^ ((row & 15) << 4));
}
__device__ __forceinline__ short8 ldfrag16(const char* base, int row0, int kbyte, int lane) {
    int row = row0 + (lane & 15);
    return *(const short8*)(base + swz128(row, kbyte + ((lane >> 4) << 4)));
}
__device__ __forceinline__ short8 ldfrag16w(const char* base, int row0, int kbyte, int lane) {
    int row = row0 + (lane & 15);
    return *(const short8*)(base + swz256(row, kbyte + ((lane >> 4) << 4)));
}
__device__ __forceinline__ short8 ldfrag32(const char* base, int row0, int colbyte, int lane) {
    int row = row0 + (lane & 31);
    return *(const short8*)(base + swz128(row, colbyte + ((lane >> 5) << 4)));
}
__device__ __forceinline__ short8 wfragT(const unsigned short* __restrict__ wT, int nt, int kc, int lane) {
    int j  = nt * 16 + (lane & 15);
    int k0 = kc * 32 + ((lane >> 4) & 3) * 8;
    return *(const short8*)(wT + j * 64 + k0);
}
__device__ __forceinline__ f32x4 zero4() {
    f32x4 v = {0.f, 0.f, 0.f, 0.f};
    return v;
}
__device__ __forceinline__ f32x16 zero16() {
    f32x16 v = {0.f, 0.f, 0.f, 0.f, 0.f, 0.f, 0.f, 0.f,
                0.f, 0.f, 0.f, 0.f, 0.f, 0.f, 0.f, 0.f};
    return v;
}

// LayerNorm in swapped layout: lane (g,lam) holds feats nt*16+g*4+r of token lam
__device__ __forceinline__ void lnS(float (&z)[2][4][4]) {
#pragma unroll
    for (int mi = 0; mi < 2; ++mi) {
        float s = 0.f;
#pragma unroll
        for (int nt = 0; nt < 4; ++nt)
#pragma unroll
        for (int r = 0; r < 4; ++r) s += z[mi][nt][r];
        s += __shfl_xor(s, 16); s += __shfl_xor(s, 32);
        float mean = s * 0.015625f;
        float q = 0.f;
#pragma unroll
        for (int nt = 0; nt < 4; ++nt)
#pragma unroll
        for (int r = 0; r < 4; ++r) { z[mi][nt][r] -= mean; q += z[mi][nt][r] * z[mi][nt][r]; }
        q += __shfl_xor(q, 16); q += __shfl_xor(q, 32);
        float rstd = __builtin_amdgcn_rsqf(q * 0.015625f + 1e-5f);
#pragma unroll
        for (int nt = 0; nt < 4; ++nt)
#pragma unroll
        for (int r = 0; r < 4; ++r) z[mi][nt][r] *= rstd;
    }
}

// prologue: ws[w][j][k] = bf16(W_w[k][j]) — transposed k-major bf16 weights
__global__ void prep_weights(const float* __restrict__ Wq, const float* __restrict__ Wk,
                             const float* __restrict__ Wv, const float* __restrict__ Wo,
                             const float* __restrict__ Wf1, const float* __restrict__ Wf2,
                             unsigned short* __restrict__ ws) {
    const float* Ws[6] = {Wq, Wk, Wv, Wo, Wf1, Wf2};
    const float* W = Ws[blockIdx.x];
    unsigned short* o = ws + blockIdx.x * 4096;
#pragma unroll
    for (int i = 0; i < 16; ++i) {
        int idx = i * 256 + threadIdx.x;
        int j = idx >> 6, k = idx & 63;
        o[idx] = f2bf(W[k * 64 + j]);
    }
}

__global__ __launch_bounds__(256, 3)
void ta_fused(const float* __restrict__ x, const float* __restrict__ te,
              const unsigned short* __restrict__ wT,
              const float* __restrict__ bq, const float* __restrict__ bk,
              const float* __restrict__ bv, const float* __restrict__ bo,
              const float* __restrict__ bf1, const float* __restrict__ bf2,
              float* __restrict__ out)
{
    // 32 KB total: LDS permits 5 blocks/CU; VGPR at ~84 permits 6 — occupancy LDS-bound at 5
    __shared__ __align__(16) char sKb[16384];   // Q-bounce (own rows) -> K [128][64] -> O/val/h1 bounce (own rows)
    __shared__ __align__(16) char sVt[16384];   // V^T [64][128] swz256

    const int tid  = threadIdx.x;
    const int lane = tid & 63;
    const int wv   = tid >> 6;
    const int lam  = lane & 15;
    const int g    = (lane >> 4) & 3;
    const int bid  = blockIdx.x;
    const int b    = bid / N_;
    const int n    = bid - b * N_;
    const long long base = ((long long)b * T_ * N_ + n) * F_;
    const int t0w = wv * 32;

    // ---------------- P0: X = x + te straight into fragments ----------------
    short8 ax[2][2];
#pragma unroll
    for (int mi = 0; mi < 2; ++mi) {
        const float* xr = x  + base + (long long)(t0w + mi * 16 + lam) * ROWSTRIDE;
        const float* tr = te + base + (long long)(t0w + mi * 16 + lam) * ROWSTRIDE;
#pragma unroll
        for (int kc = 0; kc < 2; ++kc) {
            int f0 = kc * 32 + g * 8;
            float4 a0 = *(const float4*)(xr + f0);
            float4 a1 = *(const float4*)(xr + f0 + 4);
            float4 c0 = *(const float4*)(tr + f0);
            float4 c1 = *(const float4*)(tr + f0 + 4);
            U4 u;
            u.u[0] = cvtpk(a0.x + c0.x, a0.y + c0.y);
            u.u[1] = cvtpk(a0.z + c0.z, a0.w + c0.w);
            u.u[2] = cvtpk(a1.x + c1.x, a1.y + c1.y);
            u.u[3] = cvtpk(a1.z + c1.z, a1.w + c1.w);
            ax[mi][kc] = u.s;
        }
    }

    short8 qf[4];   // per-head Q B-fragments, live through P2 (16 VGPRs)

    // ---------------- P1: Q (bounce in own K rows) -> K (overwrite) -> V ----------------
    {
        // --- Q, swapped orientation D[j][t] ---
        {
            const unsigned short* wTp = wT;
            short8 bw[4][2]; float4 bj[4];
#pragma unroll
            for (int nt = 0; nt < 4; ++nt) {
                bw[nt][0] = wfragT(wTp, nt, 0, lane);
                bw[nt][1] = wfragT(wTp, nt, 1, lane);
                bj[nt]    = *(const float4*)(bq + nt * 16 + g * 4);
            }
            f32x4 acc[2][4];
#pragma unroll
            for (int mi = 0; mi < 2; ++mi)
#pragma unroll
            for (int nt = 0; nt < 4; ++nt) acc[mi][nt] = zero4();
#pragma unroll
            for (int kc = 0; kc < 2; ++kc)
#pragma unroll
            for (int mi = 0; mi < 2; ++mi)
#pragma unroll
            for (int nt = 0; nt < 4; ++nt)
                acc[mi][nt] = __builtin_amdgcn_mfma_f32_16x16x32_bf16(bw[nt][kc], ax[mi][kc], acc[mi][nt], 0, 0, 0);
#pragma unroll
            for (int mi = 0; mi < 2; ++mi)
#pragma unroll
            for (int nt = 0; nt < 4; ++nt) {
                unsigned d0 = cvtpk(acc[mi][nt][0] + bj[nt].x, acc[mi][nt][1] + bj[nt].y);
                unsigned d1 = cvtpk(acc[mi][nt][2] + bj[nt].z, acc[mi][nt][3] + bj[nt].w);
                unsigned long long pk = (unsigned long long)d0 | ((unsigned long long)d1 << 32);
                *(unsigned long long*)(sKb + swz128(t0w + mi * 16 + lam, (nt * 16 + g * 4) * 2)) = pk;
            }
            // read back Q as per-head B-fragments (wave-private rows; program order)
#pragma unroll
            for (int h = 0; h < 4; ++h) qf[h] = ldfrag32(sKb, t0w, h * 32, lane);
        }
        // --- K, swapped orientation, overwrites the Q bounce (own rows) ---
        {
            const unsigned short* wTp = wT + 4096;
            short8 bw[4][2]; float4 bj[4];
#pragma unroll
            for (int nt = 0; nt < 4; ++nt) {
                bw[nt][0] = wfragT(wTp, nt, 0, lane);
                bw[nt][1] = wfragT(wTp, nt, 1, lane);
                bj[nt]    = *(const float4*)(bk + nt * 16 + g * 4);
            }
            f32x4 acc[2][4];
#pragma unroll
            for (int mi = 0; mi < 2; ++mi)
#pragma unroll
            for (int nt = 0; nt < 4; ++nt) acc[mi][nt] = zero4();
#pragma unroll
            for (int kc = 0; kc < 2; ++kc)
#pragma unroll
            for (int mi = 0; mi < 2; ++mi)
#pragma unroll
            for (int nt = 0; nt < 4; ++nt)
                acc[mi][nt] = __builtin_amdgcn_mfma_f32_16x16x32_bf16(bw[nt][kc], ax[mi][kc], acc[mi][nt], 0, 0, 0);
#pragma unroll
            for (int mi = 0; mi < 2; ++mi)
#pragma unroll
            for (int nt = 0; nt < 4; ++nt) {
                unsigned d0 = cvtpk(acc[mi][nt][0] + bj[nt].x, acc[mi][nt][1] + bj[nt].y);
                unsigned d1 = cvtpk(acc[mi][nt][2] + bj[nt].z, acc[mi][nt][3] + bj[nt].w);
                unsigned long long pk = (unsigned long long)d0 | ((unsigned long long)d1 << 32);
                *(unsigned long long*)(sKb + swz128(t0w + mi * 16 + lam, (nt * 16 + g * 4) * 2)) = pk;
            }
        }
        // --- V, normal orientation -> V^T ---
        {
            const unsigned short* wTp = wT + 2 * 4096;
            short8 bw[4][2]; float bias[4];
#pragma unroll
            for (int nt = 0; nt < 4; ++nt) {
                bw[nt][0] = wfragT(wTp, nt, 0, lane);
                bw[nt][1] = wfragT(wTp, nt, 1, lane);
                bias[nt]  = bv[nt * 16 + lam];
            }
            f32x4 acc[2][4];
#pragma unroll
            for (int mi = 0; mi < 2; ++mi)
#pragma unroll
            for (int nt = 0; nt < 4; ++nt) acc[mi][nt] = zero4();
#pragma unroll
            for (int kc = 0; kc < 2; ++kc)
#pragma unroll
            for (int mi = 0; mi < 2; ++mi)
#pragma unroll
            for (int nt = 0; nt < 4; ++nt)
                acc[mi][nt] = __builtin_amdgcn_mfma_f32_16x16x32_bf16(ax[mi][kc], bw[nt][kc], acc[mi][nt], 0, 0, 0);
#pragma unroll
            for (int mi = 0; mi < 2; ++mi)
#pragma unroll
            for (int nt = 0; nt < 4; ++nt) {
                int f   = nt * 16 + lam;
                int tb0 = t0w + mi * 16 + g * 4;
                unsigned d0 = cvtpk(acc[mi][nt][0] + bias[nt], acc[mi][nt][1] + bias[nt]);
                unsigned d1 = cvtpk(acc[mi][nt][2] + bias[nt], acc[mi][nt][3] + bias[nt]);
                unsigned long long pkv = (unsigned long long)d0 | ((unsigned long long)d1 << 32);
                *(unsigned long long*)(sVt + swz256(f, tb0 * 2)) = pkv;
            }
        }
    }
    __syncthreads();   // barrier 1: K and V^T valid for all waves

    // ---------------- P2: attention, single-pass no-max softmax (scores provably < overflow) ----------------
    f32x4 oaccT[4][2];
    {
        const int tcol = lane & 31;
        const int hi4  = (lane >> 5) * 4;
#pragma unroll
        for (int h = 0; h < 4; ++h) {
            float sum = 0.f;
            f32x4 o0 = zero4(), o1 = zero4();
#pragma unroll
            for (int sb = 0; sb < 4; ++sb) {
                if (sb > wv) continue;       // causal: s-tiles 0..wv (wave-uniform)
                short8 kf = ldfrag32(sKb, sb * 32, h * 32, lane);
                __builtin_amdgcn_s_setprio(1);
                f32x16 s = __builtin_amdgcn_mfma_f32_32x32x16_bf16(kf, qf[h], zero16(), 0, 0, 0);
                __builtin_amdgcn_s_setprio(0);
                if (sb == wv) {              // diagonal tile mask
#pragma unroll
                    for (int r = 0; r < 16; ++r) {
                        int srow = (r & 3) + 8 * (r >> 2) + hi4;
                        if (srow > tcol) s[r] = -3.0e38f;
                    }
                }
                float ps[16];
#pragma unroll
                for (int r = 0; r < 16; ++r) ps[r] = __expf(s[r] * 0.25f);  // no-max: exp(s/sqrt(D))
                // pairwise sum tree (4 dep levels)
                {
                    float a0 = ps[0] + ps[1],  a1 = ps[2] + ps[3];
                    float a2 = ps[4] + ps[5],  a3 = ps[6] + ps[7];
                    float a4 = ps[8] + ps[9],  a5 = ps[10] + ps[11];
                    float a6 = ps[12] + ps[13], a7 = ps[14] + ps[15];
                    sum += ((a0 + a1) + (a2 + a3)) + ((a4 + a5) + (a6 + a7));
                }
                unsigned a0 = cvtpk(ps[0],  ps[1]);
                unsigned a1 = cvtpk(ps[4],  ps[5]);
                unsigned a2 = cvtpk(ps[8],  ps[9]);
                unsigned a3 = cvtpk(ps[12], ps[13]);
                unsigned b0 = cvtpk(ps[2],  ps[3]);
                unsigned b1 = cvtpk(ps[6],  ps[7]);
                unsigned b2 = cvtpk(ps[10], ps[11]);
                unsigned b3 = cvtpk(ps[14], ps[15]);
                asm("v_permlane32_swap_b32 %0, %1" : "+v"(a0), "+v"(a2));
                asm("v_permlane32_swap_b32 %0, %1" : "+v"(a1), "+v"(a3));
                asm("v_permlane16_swap_b32 %0, %1" : "+v"(a0), "+v"(a1));
                asm("v_permlane16_swap_b32 %0, %1" : "+v"(a2), "+v"(a3));
                asm("v_permlane32_swap_b32 %0, %1" : "+v"(b0), "+v"(b2));
                asm("v_permlane32_swap_b32 %0, %1" : "+v"(b1), "+v"(b3));
                asm("v_permlane16_swap_b32 %0, %1" : "+v"(b0), "+v"(b1));
                asm("v_permlane16_swap_b32 %0, %1" : "+v"(b2), "+v"(b3));
                U4 F0, F1;
                F0.u[0] = a0; F0.u[1] = b0; F0.u[2] = a2; F0.u[3] = b2; // t-local 0..15
                F1.u[0] = a1; F1.u[1] = b1; F1.u[2] = a3; F1.u[3] = b3; // t-local 16..31
                short8 vf = ldfrag16w(sVt, h * 16, sb * 64, lane);
                __builtin_amdgcn_s_setprio(1);
                o0 = __builtin_amdgcn_mfma_f32_16x16x32_bf16(vf, F0.s, o0, 0, 0, 0);
                o1 = __builtin_amdgcn_mfma_f32_16x16x32_bf16(vf, F1.s, o1, 0, 0, 0);
                __builtin_amdgcn_s_setprio(0);
            }
            sum += __shfl_xor(sum, 32);
            float rs = __builtin_amdgcn_rcpf(sum);
            // align rs to MFMA output columns: token = lam (F0) / lam+16 (F1)
            float rs0 = __shfl(rs, lam);
            float rs1 = __shfl(rs, lam + 16);
#pragma unroll
            for (int r = 0; r < 4; ++r) {
                oaccT[h][0][r] = o0[r] * rs0;
                oaccT[h][1][r] = o1[r] * rs1;
            }
        }
    }
    __syncthreads();   // barrier 2: all waves done reading K/V; sKb own rows reusable

    // O -> bounce in own K rows (wave-private from here on)
#pragma unroll
    for (int h = 0; h < 4; ++h)
#pragma unroll
    for (int mi = 0; mi < 2; ++mi) {
        unsigned d0 = cvtpk(oaccT[h][mi][0], oaccT[h][mi][1]);
        unsigned d1 = cvtpk(oaccT[h][mi][2], oaccT[h][mi][3]);
        unsigned long long pk = (unsigned long long)d0 | ((unsigned long long)d1 << 32);
        *(unsigned long long*)(sKb + swz128(t0w + mi * 16 + lam, (h * 16 + g * 4) * 2)) = pk;
    }

    // ---------------- P3: Wo + residual (x/te re-read) + LN ----------------
    float val[2][4][4];
    {
        short8 af[2][2];
#pragma unroll
        for (int mi = 0; mi < 2; ++mi)
#pragma unroll
        for (int kc = 0; kc < 2; ++kc) af[mi][kc] = ldfrag16(sKb, t0w + mi * 16, kc * 64, lane);
        const unsigned short* wTp = wT + 3 * 4096;
        short8 bwf[4][2]; float4 bj[4];
#pragma unroll
        for (int nt = 0; nt < 4; ++nt) {
            bwf[nt][0] = wfragT(wTp, nt, 0, lane);
            bwf[nt][1] = wfragT(wTp, nt, 1, lane);
            bj[nt]     = *(const float4*)(bo + nt * 16 + g * 4);
        }
        f32x4 acc[2][4];
#pragma unroll
        for (int mi = 0; mi < 2; ++mi)
#pragma unroll
        for (int nt = 0; nt < 4; ++nt) acc[mi][nt] = zero4();
#pragma unroll
        for (int kc = 0; kc < 2; ++kc)
#pragma unroll
        for (int mi = 0; mi < 2; ++mi)
#pragma unroll
        for (int nt = 0; nt < 4; ++nt)
            acc[mi][nt] = __builtin_amdgcn_mfma_f32_16x16x32_bf16(bwf[nt][kc], af[mi][kc], acc[mi][nt], 0, 0, 0);
#pragma unroll
        for (int mi = 0; mi < 2; ++mi)
#pragma unroll
        for (int nt = 0; nt < 4; ++nt) {
            long long roff = base + (long long)(t0w + mi * 16 + lam) * ROWSTRIDE + nt * 16 + g * 4;
            float4 xv = *(const float4*)(x + roff);
            float4 tv = *(const float4*)(te + roff);
            val[mi][nt][0] = acc[mi][nt][0] + bj[nt].x + xv.x + tv.x;
            val[mi][nt][1] = acc[mi][nt][1] + bj[nt].y + xv.y + tv.y;
            val[mi][nt][2] = acc[mi][nt][2] + bj[nt].z + xv.z + tv.z;
            val[mi][nt][3] = acc[mi][nt][3] + bj[nt].w + xv.w + tv.w;
        }
        lnS(val);
#pragma unroll
        for (int mi = 0; mi < 2; ++mi)
#pragma unroll
        for (int nt = 0; nt < 4; ++nt) {
            unsigned d0 = cvtpk(val[mi][nt][0], val[mi][nt][1]);
            unsigned d1 = cvtpk(val[mi][nt][2], val[mi][nt][3]);
            unsigned long long pk = (unsigned long long)d0 | ((unsigned long long)d1 << 32);
            *(unsigned long long*)(sKb + swz128(t0w + mi * 16 + lam, (nt * 16 + g * 4) * 2)) = pk;
        }
    }

    // ---------------- P4: FF1 + ReLU ----------------
    {
        short8 af[2][2];
#pragma unroll
        for (int mi = 0; mi < 2; ++mi)
#pragma unroll
        for (int kc = 0; kc < 2; ++kc) af[mi][kc] = ldfrag16(sKb, t0w + mi * 16, kc * 64, lane);
        const unsigned short* wTp = wT + 4 * 4096;
        short8 bwf[4][2]; float4 bj[4];
#pragma unroll
        for (int nt = 0; nt < 4; ++nt) {
            bwf[nt][0] = wfragT(wTp, nt, 0, lane);
            bwf[nt][1] = wfragT(wTp, nt, 1, lane);
            bj[nt]     = *(const float4*)(bf1 + nt * 16 + g * 4);
        }
        f32x4 acc[2][4];
#pragma unroll
        for (int mi = 0; mi < 2; ++mi)
#pragma unroll
        for (int nt = 0; nt < 4; ++nt) acc[mi][nt] = zero4();
#pragma unroll
        for (int kc = 0; kc < 2; ++kc)
#pragma unroll
        for (int mi = 0; mi < 2; ++mi)
#pragma unroll
        for (int nt = 0; nt < 4; ++nt)
            acc[mi][nt] = __builtin_amdgcn_mfma_f32_16x16x32_bf16(bwf[nt][kc], af[mi][kc], acc[mi][nt], 0, 0, 0);
#pragma unroll
        for (int mi = 0; mi < 2; ++mi)
#pragma unroll
        for (int nt = 0; nt < 4; ++nt) {
            unsigned d0 = cvtpk(fmaxf(acc[mi][nt][0] + bj[nt].x, 0.f), fmaxf(acc[mi][nt][1] + bj[nt].y, 0.f));
            unsigned d1 = cvtpk(fmaxf(acc[mi][nt][2] + bj[nt].z, 0.f), fmaxf(acc[mi][nt][3] + bj[nt].w, 0.f));
            unsigned long long pk = (unsigned long long)d0 | ((unsigned long long)d1 << 32);
            *(unsigned long long*)(sKb + swz128(t0w + mi * 16 + lam, (nt * 16 + g * 4) * 2)) = pk;
        }
    }

    // ---------------- P5: FF2 + residual + LN + float4 store ----------------
    {
        short8 af[2][2];
#pragma unroll
        for (int mi = 0; mi < 2; ++mi)
#pragma unroll
        for (int kc = 0; kc < 2; ++kc) af[mi][kc] = ldfrag16(sKb, t0w + mi * 16, kc * 64, lane);
        const unsigned short* wTp = wT + 5 * 4096;
        short8 bwf[4][2]; float4 bj[4];
#pragma unroll
        for (int nt = 0; nt < 4; ++nt) {
            bwf[nt][0] = wfragT(wTp, nt, 0, lane);
            bwf[nt][1] = wfragT(wTp, nt, 1, lane);
            bj[nt]     = *(const float4*)(bf2 + nt * 16 + g * 4);
        }
        f32x4 acc[2][4];
#pragma unroll
        for (int mi = 0; mi < 2; ++mi)
#pragma unroll
        for (int nt = 0; nt < 4; ++nt) acc[mi][nt] = zero4();
#pragma unroll
        for (int kc = 0; kc < 2; ++kc)
#pragma unroll
        for (int mi = 0; mi < 2; ++mi)
#pragma unroll
        for (int nt = 0; nt < 4; ++nt)
            acc[mi][nt] = __builtin_amdgcn_mfma_f32_16x16x32_bf16(bwf[nt][kc], af[mi][kc], acc[mi][nt], 0, 0, 0);
        float z[2][4][4];
#pragma unroll
        for (int mi = 0; mi < 2; ++mi)
#pragma unroll
        for (int nt = 0; nt < 4; ++nt) {
            z[mi][nt][0] = acc[mi][nt][0] + bj[nt].x + val[mi][nt][0];
            z[mi][nt][1] = acc[mi][nt][1] + bj[nt].y + val[mi][nt][1];
            z[mi][nt][2] = acc[mi][nt][2] + bj[nt].z + val[mi][nt][2];
            z[mi][nt][3] = acc[mi][nt][3] + bj[nt].w + val[mi][nt][3];
        }
        lnS(z);
#pragma unroll
        for (int mi = 0; mi < 2; ++mi)
#pragma unroll
        for (int nt = 0; nt < 4; ++nt) {
            float4 o = {z[mi][nt][0], z[mi][nt][1], z[mi][nt][2], z[mi][nt][3]};
            *(float4*)(out + base + (long long)(t0w + mi * 16 + lam) * ROWSTRIDE + nt * 16 + g * 4) = o;
        }
    }
}

extern "C" void kernel_launch(void* const* d_in, const int* in_sizes, int n_in,
                              void* d_out, int out_size, void* d_ws, size_t ws_size,
                              hipStream_t stream) {
    const float* x   = (const float*)d_in[0];
    const float* te  = (const float*)d_in[1];
    const float* Wq  = (const float*)d_in[2];
    const float* bq  = (const float*)d_in[3];
    const float* Wk  = (const float*)d_in[4];
    const float* bk  = (const float*)d_in[5];
    const float* Wv  = (const float*)d_in[6];
    const float* bv  = (const float*)d_in[7];
    const float* Wo  = (const float*)d_in[8];
    const float* bo  = (const float*)d_in[9];
    const float* Wf1 = (const float*)d_in[10];
    const float* bf1 = (const float*)d_in[11];
    const float* Wf2 = (const float*)d_in[12];
    const float* bf2 = (const float*)d_in[13];
    unsigned short* wsT = (unsigned short*)d_ws;

    prep_weights<<<dim3(6), dim3(256), 0, stream>>>(Wq, Wk, Wv, Wo, Wf1, Wf2, wsT);
    ta_fused<<<dim3(B_ * N_), dim3(256), 0, stream>>>(
        x, te, wsT, bq, bk, bv, bo, bf1, bf2, (float*)d_out);
}

// Round 13
// 75.647 us; speedup vs baseline: 1.4214x; 1.0680x over previous
//
#include <hip/hip_runtime.h>

typedef __attribute__((ext_vector_type(8))) short short8;
typedef __attribute__((ext_vector_type(4))) float f32x4;
typedef __attribute__((ext_vector_type(16))) float f32x16;

#define B_ 8
#define T_ 128
#define N_ 170
#define F_ 64
#define ROWSTRIDE (N_ * F_) /* 10880 */

union U4 { unsigned u[4]; short8 s; };

__device__ __forceinline__ unsigned short f2bf(float f) {
    union { float f; unsigned u; } v; v.f = f;
    unsigned r = v.u + 0x7fffu + ((v.u >> 16) & 1u);
    return (unsigned short)(r >> 16);
}
__device__ __forceinline__ unsigned cvtpk(float lo, float hi) {
    unsigned d;
    asm("v_cvt_pk_bf16_f32 %0, %1, %2" : "=v"(d) : "v"(lo), "v"(hi));
    return d;
}
__device__ __forceinline__ int swz128(int row, int byteInRow) {
    return row * 128 + (byteInRow ^ ((row & 7) << 4));
}
__device__ __forceinline__ int swz256(int row, int byteInRow) {
    return row * 256 + (byteInRow ^ ((row & 15) << 4));
}
__device__ __forceinline__ short8 ldfrag16(const char* base, int row0, int kbyte, int lane) {
    int row = row0 + (lane & 15);
    return *(const short8*)(base + swz128(row, kbyte + ((lane >> 4) << 4)));
}
__device__ __forceinline__ short8 ldfrag16w(const char* base, int row0, int kbyte, int lane) {
    int row = row0 + (lane & 15);
    return *(const short8*)(base + swz256(row, kbyte + ((lane >> 4) << 4)));
}
__device__ __forceinline__ short8 ldfrag32(const char* base, int row0, int colbyte, int lane) {
    int row = row0 + (lane & 31);
    return *(const short8*)(base + swz128(row, colbyte + ((lane >> 5) << 4)));
}
__device__ __forceinline__ short8 wfragT(const unsigned short* __restrict__ wT, int nt, int kc, int lane) {
    int j  = nt * 16 + (lane & 15);
    int k0 = kc * 32 + ((lane >> 4) & 3) * 8;
    return *(const short8*)(wT + j * 64 + k0);
}
__device__ __forceinline__ f32x4 zero4() {
    f32x4 v = {0.f, 0.f, 0.f, 0.f};
    return v;
}
__device__ __forceinline__ f32x16 zero16() {
    f32x16 v = {0.f, 0.f, 0.f, 0.f, 0.f, 0.f, 0.f, 0.f,
                0.f, 0.f, 0.f, 0.f, 0.f, 0.f, 0.f, 0.f};
    return v;
}

// LayerNorm in swapped layout: lane (g,lam) holds feats nt*16+g*4+r of token lam
__device__ __forceinline__ void lnS(float (&z)[2][4][4]) {
#pragma unroll
    for (int mi = 0; mi < 2; ++mi) {
        float s = 0.f;
#pragma unroll
        for (int nt = 0; nt < 4; ++nt)
#pragma unroll
        for (int r = 0; r < 4; ++r) s += z[mi][nt][r];
        s += __shfl_xor(s, 16); s += __shfl_xor(s, 32);
        float mean = s * 0.015625f;
        float q = 0.f;
#pragma unroll
        for (int nt = 0; nt < 4; ++nt)
#pragma unroll
        for (int r = 0; r < 4; ++r) { z[mi][nt][r] -= mean; q += z[mi][nt][r] * z[mi][nt][r]; }
        q += __shfl_xor(q, 16); q += __shfl_xor(q, 32);
        float rstd = __builtin_amdgcn_rsqf(q * 0.015625f + 1e-5f);
#pragma unroll
        for (int nt = 0; nt < 4; ++nt)
#pragma unroll
        for (int r = 0; r < 4; ++r) z[mi][nt][r] *= rstd;
    }
}

// prologue: ws[w][j][k] = bf16(W_w[k][j]) — transposed k-major bf16 weights
__global__ void prep_weights(const float* __restrict__ Wq, const float* __restrict__ Wk,
                             const float* __restrict__ Wv, const float* __restrict__ Wo,
                             const float* __restrict__ Wf1, const float* __restrict__ Wf2,
                             unsigned short* __restrict__ ws) {
    const float* Ws[6] = {Wq, Wk, Wv, Wo, Wf1, Wf2};
    const float* W = Ws[blockIdx.x];
    unsigned short* o = ws + blockIdx.x * 4096;
#pragma unroll
    for (int i = 0; i < 16; ++i) {
        int idx = i * 256 + threadIdx.x;
        int j = idx >> 6, k = idx & 63;
        o[idx] = f2bf(W[k * 64 + j]);
    }
}

__global__ __launch_bounds__(256, 3)
void ta_fused(const float* __restrict__ x, const float* __restrict__ te,
              const unsigned short* __restrict__ wT,
              const float* __restrict__ bq, const float* __restrict__ bk,
              const float* __restrict__ bv, const float* __restrict__ bo,
              const float* __restrict__ bf1, const float* __restrict__ bf2,
              float* __restrict__ out)
{
    __shared__ __align__(16) char sKb[16384];   // K [128][64] swz128 (shared, read-only after barrier)
    __shared__ __align__(16) char sVt[16384];   // V^T [64][128] swz256 (shared, read-only after barrier)
    __shared__ __align__(16) char sBn[16384];   // 4x 4KB wave-private bounce: Q -> O -> val -> h1

    const int tid  = threadIdx.x;
    const int lane = tid & 63;
    const int wv   = tid >> 6;
    const int lam  = lane & 15;
    const int g    = (lane >> 4) & 3;
    const int bid  = blockIdx.x;
    const int b    = bid / N_;
    const int n    = bid - b * N_;
    const long long base = ((long long)b * T_ * N_ + n) * F_;
    const int t0w = wv * 32;
    char* myb = sBn + wv * 4096;   // this wave's 32x64 bf16 bounce tile (local rows 0..31)

    // ---------------- P0: X = x + te straight into fragments (global, coalesced) ----------------
    short8 ax[2][2];   // [mi][kc]: lane -> row t0w+mi*16+(l&15), feats kc*32+g*8..+7
#pragma unroll
    for (int mi = 0; mi < 2; ++mi) {
        const float* xr = x  + base + (long long)(t0w + mi * 16 + lam) * ROWSTRIDE;
        const float* tr = te + base + (long long)(t0w + mi * 16 + lam) * ROWSTRIDE;
#pragma unroll
        for (int kc = 0; kc < 2; ++kc) {
            int f0 = kc * 32 + g * 8;
            float4 a0 = *(const float4*)(xr + f0);
            float4 a1 = *(const float4*)(xr + f0 + 4);
            float4 c0 = *(const float4*)(tr + f0);
            float4 c1 = *(const float4*)(tr + f0 + 4);
            U4 u;
            u.u[0] = cvtpk(a0.x + c0.x, a0.y + c0.y);
            u.u[1] = cvtpk(a0.z + c0.z, a0.w + c0.w);
            u.u[2] = cvtpk(a1.x + c1.x, a1.y + c1.y);
            u.u[3] = cvtpk(a1.z + c1.z, a1.w + c1.w);
            ax[mi][kc] = u.s;
        }
    }

    // ---------------- P1: Q,K,V projections for this wave's 32 rows ----------------
    {
#pragma unroll
        for (int w = 0; w < 3; ++w) {
            const unsigned short* wTp = wT + w * 4096;
            short8 bw[4][2];
#pragma unroll
            for (int nt = 0; nt < 4; ++nt) {
                bw[nt][0] = wfragT(wTp, nt, 0, lane);
                bw[nt][1] = wfragT(wTp, nt, 1, lane);
            }
            f32x4 acc[2][4];
#pragma unroll
            for (int mi = 0; mi < 2; ++mi)
#pragma unroll
            for (int nt = 0; nt < 4; ++nt) acc[mi][nt] = zero4();

            if (w < 2) {   // SWAPPED: D[j][t] — lane holds token t=lam, feats nt*16+g*4+r
                const float* bp = (w == 0) ? bq : bk;
                float4 bj[4];
#pragma unroll
                for (int nt = 0; nt < 4; ++nt) bj[nt] = *(const float4*)(bp + nt * 16 + g * 4);
#pragma unroll
                for (int kc = 0; kc < 2; ++kc)
#pragma unroll
                for (int mi = 0; mi < 2; ++mi)
#pragma unroll
                for (int nt = 0; nt < 4; ++nt)
                    acc[mi][nt] = __builtin_amdgcn_mfma_f32_16x16x32_bf16(bw[nt][kc], ax[mi][kc], acc[mi][nt], 0, 0, 0);
#pragma unroll
                for (int mi = 0; mi < 2; ++mi)
#pragma unroll
                for (int nt = 0; nt < 4; ++nt) {
                    unsigned d0 = cvtpk(acc[mi][nt][0] + bj[nt].x, acc[mi][nt][1] + bj[nt].y);
                    unsigned d1 = cvtpk(acc[mi][nt][2] + bj[nt].z, acc[mi][nt][3] + bj[nt].w);
                    unsigned long long pk = (unsigned long long)d0 | ((unsigned long long)d1 << 32);
                    if (w == 0) {  // Q -> bounce, local rows
                        *(unsigned long long*)(myb + swz128(mi * 16 + lam, (nt * 16 + g * 4) * 2)) = pk;
                    } else {       // K -> shared, global rows
                        *(unsigned long long*)(sKb + swz128(t0w + mi * 16 + lam, (nt * 16 + g * 4) * 2)) = pk;
                    }
                }
            } else {       // V normal: D[t][f]; pack 4 consecutive t -> V^T[f][t]
                float bias[4];
#pragma unroll
                for (int nt = 0; nt < 4; ++nt) bias[nt] = bv[nt * 16 + lam];
#pragma unroll
                for (int kc = 0; kc < 2; ++kc)
#pragma unroll
                for (int mi = 0; mi < 2; ++mi)
#pragma unroll
                for (int nt = 0; nt < 4; ++nt)
                    acc[mi][nt] = __builtin_amdgcn_mfma_f32_16x16x32_bf16(ax[mi][kc], bw[nt][kc], acc[mi][nt], 0, 0, 0);
#pragma unroll
                for (int mi = 0; mi < 2; ++mi)
#pragma unroll
                for (int nt = 0; nt < 4; ++nt) {
                    int f   = nt * 16 + lam;
                    int tb0 = t0w + mi * 16 + g * 4;
                    unsigned d0 = cvtpk(acc[mi][nt][0] + bias[nt], acc[mi][nt][1] + bias[nt]);
                    unsigned d1 = cvtpk(acc[mi][nt][2] + bias[nt], acc[mi][nt][3] + bias[nt]);
                    unsigned long long pkv = (unsigned long long)d0 | ((unsigned long long)d1 << 32);
                    *(unsigned long long*)(sVt + swz256(f, tb0 * 2)) = pkv;
                }
            }
        }
    }
    __syncthreads();   // the ONLY barrier: K and V^T now valid for all waves

    // ---------------- P2: attention, single-pass no-max softmax (validated R11/R12) ----------------
    {
        const int tcol = lane & 31;
        const int hi4  = (lane >> 5) * 4;
#pragma unroll
        for (int h = 0; h < 4; ++h) {
            short8 qf = ldfrag32(myb, 0, h * 32, lane);   // B-frag of wave's own Q rows
            float sum = 0.f;
            f32x4 o0 = zero4(), o1 = zero4();
#pragma unroll
            for (int sb = 0; sb < 4; ++sb) {
                if (sb > wv) continue;       // causal: s-tiles 0..wv (wave-uniform)
                short8 kf = ldfrag32(sKb, sb * 32, h * 32, lane);
                __builtin_amdgcn_s_setprio(1);
                f32x16 s = __builtin_amdgcn_mfma_f32_32x32x16_bf16(kf, qf, zero16(), 0, 0, 0);
                __builtin_amdgcn_s_setprio(0);
                if (sb == wv) {              // diagonal tile mask (static index)
#pragma unroll
                    for (int r = 0; r < 16; ++r) {
                        int srow = (r & 3) + 8 * (r >> 2) + hi4;
                        if (srow > tcol) s[r] = -3.0e38f;
                    }
                }
                float ps[16];
#pragma unroll
                for (int r = 0; r < 16; ++r) ps[r] = __expf(s[r] * 0.25f);  // no-max: exp(s/sqrt(D))
                {   // pairwise sum tree (4 dep levels)
                    float a0 = ps[0] + ps[1],  a1 = ps[2] + ps[3];
                    float a2 = ps[4] + ps[5],  a3 = ps[6] + ps[7];
                    float a4 = ps[8] + ps[9],  a5 = ps[10] + ps[11];
                    float a6 = ps[12] + ps[13], a7 = ps[14] + ps[15];
                    sum += ((a0 + a1) + (a2 + a3)) + ((a4 + a5) + (a6 + a7));
                }
                unsigned a0 = cvtpk(ps[0],  ps[1]);
                unsigned a1 = cvtpk(ps[4],  ps[5]);
                unsigned a2 = cvtpk(ps[8],  ps[9]);
                unsigned a3 = cvtpk(ps[12], ps[13]);
                unsigned b0 = cvtpk(ps[2],  ps[3]);
                unsigned b1 = cvtpk(ps[6],  ps[7]);
                unsigned b2 = cvtpk(ps[10], ps[11]);
                unsigned b3 = cvtpk(ps[14], ps[15]);
                asm("v_permlane32_swap_b32 %0, %1" : "+v"(a0), "+v"(a2));
                asm("v_permlane32_swap_b32 %0, %1" : "+v"(a1), "+v"(a3));
                asm("v_permlane16_swap_b32 %0, %1" : "+v"(a0), "+v"(a1));
                asm("v_permlane16_swap_b32 %0, %1" : "+v"(a2), "+v"(a3));
                asm("v_permlane32_swap_b32 %0, %1" : "+v"(b0), "+v"(b2));
                asm("v_permlane32_swap_b32 %0, %1" : "+v"(b1), "+v"(b3));
                asm("v_permlane16_swap_b32 %0, %1" : "+v"(b0), "+v"(b1));
                asm("v_permlane16_swap_b32 %0, %1" : "+v"(b2), "+v"(b3));
                U4 F0, F1;
                F0.u[0] = a0; F0.u[1] = b0; F0.u[2] = a2; F0.u[3] = b2; // t-local 0..15
                F1.u[0] = a1; F1.u[1] = b1; F1.u[2] = a3; F1.u[3] = b3; // t-local 16..31
                short8 vf = ldfrag16w(sVt, h * 16, sb * 64, lane);
                __builtin_amdgcn_s_setprio(1);
                o0 = __builtin_amdgcn_mfma_f32_16x16x32_bf16(vf, F0.s, o0, 0, 0, 0);
                o1 = __builtin_amdgcn_mfma_f32_16x16x32_bf16(vf, F1.s, o1, 0, 0, 0);
                __builtin_amdgcn_s_setprio(0);
            }
            sum += __shfl_xor(sum, 32);
            float rs = __builtin_amdgcn_rcpf(sum);
            // align rs to MFMA output columns: token = lam (F0) / lam+16 (F1)
            float rs0 = __shfl(rs, lam);
            float rs1 = __shfl(rs, lam + 16);
            // O -> bounce (overwrites Q rows for this head; wave-private, no barrier)
#pragma unroll
            for (int mi = 0; mi < 2; ++mi) {
                f32x4 ov = (mi == 0) ? o0 : o1;
                float rsm = (mi == 0) ? rs0 : rs1;
                unsigned d0 = cvtpk(ov[0] * rsm, ov[1] * rsm);
                unsigned d1 = cvtpk(ov[2] * rsm, ov[3] * rsm);
                unsigned long long pk = (unsigned long long)d0 | ((unsigned long long)d1 << 32);
                *(unsigned long long*)(myb + swz128(mi * 16 + lam, (h * 16 + g * 4) * 2)) = pk;
            }
        }
    }
    // everything below is wave-private: ZERO barriers to the end

    // ---------------- P3: Wo + residual(X re-read, float4) + LN ----------------
    float val[2][4][4];
    {
        short8 af[2][2];
#pragma unroll
        for (int mi = 0; mi < 2; ++mi)
#pragma unroll
        for (int kc = 0; kc < 2; ++kc) af[mi][kc] = ldfrag16(myb, mi * 16, kc * 64, lane);
        const unsigned short* wTp = wT + 3 * 4096;
        short8 bwf[4][2]; float4 bj[4];
#pragma unroll
        for (int nt = 0; nt < 4; ++nt) {
            bwf[nt][0] = wfragT(wTp, nt, 0, lane);
            bwf[nt][1] = wfragT(wTp, nt, 1, lane);
            bj[nt]     = *(const float4*)(bo + nt * 16 + g * 4);
        }
        f32x4 acc[2][4];
#pragma unroll
        for (int mi = 0; mi < 2; ++mi)
#pragma unroll
        for (int nt = 0; nt < 4; ++nt) acc[mi][nt] = zero4();
#pragma unroll
        for (int kc = 0; kc < 2; ++kc)
#pragma unroll
        for (int mi = 0; mi < 2; ++mi)
#pragma unroll
        for (int nt = 0; nt < 4; ++nt)
            acc[mi][nt] = __builtin_amdgcn_mfma_f32_16x16x32_bf16(bwf[nt][kc], af[mi][kc], acc[mi][nt], 0, 0, 0);
#pragma unroll
        for (int mi = 0; mi < 2; ++mi)
#pragma unroll
        for (int nt = 0; nt < 4; ++nt) {
            long long roff = base + (long long)(t0w + mi * 16 + lam) * ROWSTRIDE + nt * 16 + g * 4;
            float4 xv = *(const float4*)(x + roff);
            float4 tv = *(const float4*)(te + roff);
            val[mi][nt][0] = acc[mi][nt][0] + bj[nt].x + xv.x + tv.x;
            val[mi][nt][1] = acc[mi][nt][1] + bj[nt].y + xv.y + tv.y;
            val[mi][nt][2] = acc[mi][nt][2] + bj[nt].z + xv.z + tv.z;
            val[mi][nt][3] = acc[mi][nt][3] + bj[nt].w + xv.w + tv.w;
        }
        lnS(val);
#pragma unroll
        for (int mi = 0; mi < 2; ++mi)
#pragma unroll
        for (int nt = 0; nt < 4; ++nt) {
            unsigned d0 = cvtpk(val[mi][nt][0], val[mi][nt][1]);
            unsigned d1 = cvtpk(val[mi][nt][2], val[mi][nt][3]);
            unsigned long long pk = (unsigned long long)d0 | ((unsigned long long)d1 << 32);
            *(unsigned long long*)(myb + swz128(mi * 16 + lam, (nt * 16 + g * 4) * 2)) = pk;
        }
    }

    // ---------------- P4: FF1 + ReLU ----------------
    {
        short8 af[2][2];
#pragma unroll
        for (int mi = 0; mi < 2; ++mi)
#pragma unroll
        for (int kc = 0; kc < 2; ++kc) af[mi][kc] = ldfrag16(myb, mi * 16, kc * 64, lane);
        const unsigned short* wTp = wT + 4 * 4096;
        short8 bwf[4][2]; float4 bj[4];
#pragma unroll
        for (int nt = 0; nt < 4; ++nt) {
            bwf[nt][0] = wfragT(wTp, nt, 0, lane);
            bwf[nt][1] = wfragT(wTp, nt, 1, lane);
            bj[nt]     = *(const float4*)(bf1 + nt * 16 + g * 4);
        }
        f32x4 acc[2][4];
#pragma unroll
        for (int mi = 0; mi < 2; ++mi)
#pragma unroll
        for (int nt = 0; nt < 4; ++nt) acc[mi][nt] = zero4();
#pragma unroll
        for (int kc = 0; kc < 2; ++kc)
#pragma unroll
        for (int mi = 0; mi < 2; ++mi)
#pragma unroll
        for (int nt = 0; nt < 4; ++nt)
            acc[mi][nt] = __builtin_amdgcn_mfma_f32_16x16x32_bf16(bwf[nt][kc], af[mi][kc], acc[mi][nt], 0, 0, 0);
#pragma unroll
        for (int mi = 0; mi < 2; ++mi)
#pragma unroll
        for (int nt = 0; nt < 4; ++nt) {
            unsigned d0 = cvtpk(fmaxf(acc[mi][nt][0] + bj[nt].x, 0.f), fmaxf(acc[mi][nt][1] + bj[nt].y, 0.f));
            unsigned d1 = cvtpk(fmaxf(acc[mi][nt][2] + bj[nt].z, 0.f), fmaxf(acc[mi][nt][3] + bj[nt].w, 0.f));
            unsigned long long pk = (unsigned long long)d0 | ((unsigned long long)d1 << 32);
            *(unsigned long long*)(myb + swz128(mi * 16 + lam, (nt * 16 + g * 4) * 2)) = pk;
        }
    }

    // ---------------- P5: FF2 + residual + LN + float4 store ----------------
    {
        short8 af[2][2];
#pragma unroll
        for (int mi = 0; mi < 2; ++mi)
#pragma unroll
        for (int kc = 0; kc < 2; ++kc) af[mi][kc] = ldfrag16(myb, mi * 16, kc * 64, lane);
        const unsigned short* wTp = wT + 5 * 4096;
        short8 bwf[4][2]; float4 bj[4];
#pragma unroll
        for (int nt = 0; nt < 4; ++nt) {
            bwf[nt][0] = wfragT(wTp, nt, 0, lane);
            bwf[nt][1] = wfragT(wTp, nt, 1, lane);
            bj[nt]     = *(const float4*)(bf2 + nt * 16 + g * 4);
        }
        f32x4 acc[2][4];
#pragma unroll
        for (int mi = 0; mi < 2; ++mi)
#pragma unroll
        for (int nt = 0; nt < 4; ++nt) acc[mi][nt] = zero4();
#pragma unroll
        for (int kc = 0; kc < 2; ++kc)
#pragma unroll
        for (int mi = 0; mi < 2; ++mi)
#pragma unroll
        for (int nt = 0; nt < 4; ++nt)
            acc[mi][nt] = __builtin_amdgcn_mfma_f32_16x16x32_bf16(bwf[nt][kc], af[mi][kc], acc[mi][nt], 0, 0, 0);
        float z[2][4][4];
#pragma unroll
        for (int mi = 0; mi < 2; ++mi)
#pragma unroll
        for (int nt = 0; nt < 4; ++nt) {
            z[mi][nt][0] = acc[mi][nt][0] + bj[nt].x + val[mi][nt][0];
            z[mi][nt][1] = acc[mi][nt][1] + bj[nt].y + val[mi][nt][1];
            z[mi][nt][2] = acc[mi][nt][2] + bj[nt].z + val[mi][nt][2];
            z[mi][nt][3] = acc[mi][nt][3] + bj[nt].w + val[mi][nt][3];
        }
        lnS(z);
#pragma unroll
        for (int mi = 0; mi < 2; ++mi)
#pragma unroll
        for (int nt = 0; nt < 4; ++nt) {
            float4 o = {z[mi][nt][0], z[mi][nt][1], z[mi][nt][2], z[mi][nt][3]};
            *(float4*)(out + base + (long long)(t0w + mi * 16 + lam) * ROWSTRIDE + nt * 16 + g * 4) = o;
        }
    }
}

extern "C" void kernel_launch(void* const* d_in, const int* in_sizes, int n_in,
                              void* d_out, int out_size, void* d_ws, size_t ws_size,
                              hipStream_t stream) {
    const float* x   = (const float*)d_in[0];
    const float* te  = (const float*)d_in[1];
    const float* Wq  = (const float*)d_in[2];
    const float* bq  = (const float*)d_in[3];
    const float* Wk  = (const float*)d_in[4];
    const float* bk  = (const float*)d_in[5];
    const float* Wv  = (const float*)d_in[6];
    const float* bv  = (const float*)d_in[7];
    const float* Wo  = (const float*)d_in[8];
    const float* bo  = (const float*)d_in[9];
    const float* Wf1 = (const float*)d_in[10];
    const float* bf1 = (const float*)d_in[11];
    const float* Wf2 = (const float*)d_in[12];
    const float* bf2 = (const float*)d_in[13];
    unsigned short* wsT = (unsigned short*)d_ws;

    prep_weights<<<dim3(6), dim3(256), 0, stream>>>(Wq, Wk, Wv, Wo, Wf1, Wf2, wsT);
    ta_fused<<<dim3(B_ * N_), dim3(256), 0, stream>>>(
        x, te, wsT, bq, bk, bv, bo, bf1, bf2, (float*)d_out);
}

// Round 14
// 74.059 us; speedup vs baseline: 1.4518x; 1.0214x over previous
//
#include <hip/hip_runtime.h>

typedef __attribute__((ext_vector_type(8))) short short8;
typedef __attribute__((ext_vector_type(4))) float f32x4;
typedef __attribute__((ext_vector_type(16))) float f32x16;

#define B_ 8
#define T_ 128
#define N_ 170
#define F_ 64
#define ROWSTRIDE (N_ * F_) /* 10880 */

union U4 { unsigned u[4]; short8 s; };

__device__ __forceinline__ unsigned short f2bf(float f) {
    union { float f; unsigned u; } v; v.f = f;
    unsigned r = v.u + 0x7fffu + ((v.u >> 16) & 1u);
    return (unsigned short)(r >> 16);
}
__device__ __forceinline__ unsigned cvtpk(float lo, float hi) {
    unsigned d;
    asm("v_cvt_pk_bf16_f32 %0, %1, %2" : "=v"(d) : "v"(lo), "v"(hi));
    return d;
}
__device__ __forceinline__ int swz128(int row, int byteInRow) {
    return row * 128 + (byteInRow ^ ((row & 7) << 4));
}
__device__ __forceinline__ int swz256(int row, int byteInRow) {
    return row * 256 + (byteInRow ^ ((row & 15) << 4));
}
__device__ __forceinline__ short8 ldfrag16(const char* base, int row0, int kbyte, int lane) {
    int row = row0 + (lane & 15);
    return *(const short8*)(base + swz128(row, kbyte + ((lane >> 4) << 4)));
}
__device__ __forceinline__ short8 ldfrag16w(const char* base, int row0, int kbyte, int lane) {
    int row = row0 + (lane & 15);
    return *(const short8*)(base + swz256(row, kbyte + ((lane >> 4) << 4)));
}
__device__ __forceinline__ short8 ldfrag32(const char* base, int row0, int colbyte, int lane) {
    int row = row0 + (lane & 31);
    return *(const short8*)(base + swz128(row, colbyte + ((lane >> 5) << 4)));
}
__device__ __forceinline__ short8 wfragT(const unsigned short* __restrict__ wT, int nt, int kc, int lane) {
    int j  = nt * 16 + (lane & 15);
    int k0 = kc * 32 + ((lane >> 4) & 3) * 8;
    return *(const short8*)(wT + j * 64 + k0);
}
__device__ __forceinline__ f32x4 zero4() {
    f32x4 v = {0.f, 0.f, 0.f, 0.f};
    return v;
}
__device__ __forceinline__ f32x16 zero16() {
    f32x16 v = {0.f, 0.f, 0.f, 0.f, 0.f, 0.f, 0.f, 0.f,
                0.f, 0.f, 0.f, 0.f, 0.f, 0.f, 0.f, 0.f};
    return v;
}

// LayerNorm in swapped layout: lane (g,lam) holds feats nt*16+g*4+r of token lam
__device__ __forceinline__ void lnS(float (&z)[2][4][4]) {
#pragma unroll
    for (int mi = 0; mi < 2; ++mi) {
        float s = 0.f;
#pragma unroll
        for (int nt = 0; nt < 4; ++nt)
#pragma unroll
        for (int r = 0; r < 4; ++r) s += z[mi][nt][r];
        s += __shfl_xor(s, 16); s += __shfl_xor(s, 32);
        float mean = s * 0.015625f;
        float q = 0.f;
#pragma unroll
        for (int nt = 0; nt < 4; ++nt)
#pragma unroll
        for (int r = 0; r < 4; ++r) { z[mi][nt][r] -= mean; q += z[mi][nt][r] * z[mi][nt][r]; }
        q += __shfl_xor(q, 16); q += __shfl_xor(q, 32);
        float rstd = __builtin_amdgcn_rsqf(q * 0.015625f + 1e-5f);
#pragma unroll
        for (int nt = 0; nt < 4; ++nt)
#pragma unroll
        for (int r = 0; r < 4; ++r) z[mi][nt][r] *= rstd;
    }
}

// 16-element exp + pairwise-tree sum + bf16 pack + permlane transpose -> two A-frags
__device__ __forceinline__ void softpack(const f32x16& s, float& sum, U4& F0, U4& F1) {
    const float E = 0.36067376022224085f;   // 0.25/ln2 : exp(s/4)=exp2(s*E)
    float ps[16];
#pragma unroll
    for (int r = 0; r < 16; ++r) ps[r] = exp2f(s[r] * E);
    {
        float a0 = ps[0] + ps[1],  a1 = ps[2] + ps[3];
        float a2 = ps[4] + ps[5],  a3 = ps[6] + ps[7];
        float a4 = ps[8] + ps[9],  a5 = ps[10] + ps[11];
        float a6 = ps[12] + ps[13], a7 = ps[14] + ps[15];
        sum += ((a0 + a1) + (a2 + a3)) + ((a4 + a5) + (a6 + a7));
    }
    unsigned a0 = cvtpk(ps[0],  ps[1]);
    unsigned a1 = cvtpk(ps[4],  ps[5]);
    unsigned a2 = cvtpk(ps[8],  ps[9]);
    unsigned a3 = cvtpk(ps[12], ps[13]);
    unsigned b0 = cvtpk(ps[2],  ps[3]);
    unsigned b1 = cvtpk(ps[6],  ps[7]);
    unsigned b2 = cvtpk(ps[10], ps[11]);
    unsigned b3 = cvtpk(ps[14], ps[15]);
    asm("v_permlane32_swap_b32 %0, %1" : "+v"(a0), "+v"(a2));
    asm("v_permlane32_swap_b32 %0, %1" : "+v"(a1), "+v"(a3));
    asm("v_permlane16_swap_b32 %0, %1" : "+v"(a0), "+v"(a1));
    asm("v_permlane16_swap_b32 %0, %1" : "+v"(a2), "+v"(a3));
    asm("v_permlane32_swap_b32 %0, %1" : "+v"(b0), "+v"(b2));
    asm("v_permlane32_swap_b32 %0, %1" : "+v"(b1), "+v"(b3));
    asm("v_permlane16_swap_b32 %0, %1" : "+v"(b0), "+v"(b1));
    asm("v_permlane16_swap_b32 %0, %1" : "+v"(b2), "+v"(b3));
    F0.u[0] = a0; F0.u[1] = b0; F0.u[2] = a2; F0.u[3] = b2; // t-local 0..15
    F1.u[0] = a1; F1.u[1] = b1; F1.u[2] = a3; F1.u[3] = b3; // t-local 16..31
}

// prologue: ws[w][j][k] = bf16(W_w[k][j]) — transposed k-major bf16 weights
__global__ void prep_weights(const float* __restrict__ Wq, const float* __restrict__ Wk,
                             const float* __restrict__ Wv, const float* __restrict__ Wo,
                             const float* __restrict__ Wf1, const float* __restrict__ Wf2,
                             unsigned short* __restrict__ ws) {
    const float* Ws[6] = {Wq, Wk, Wv, Wo, Wf1, Wf2};
    const float* W = Ws[blockIdx.x];
    unsigned short* o = ws + blockIdx.x * 4096;
#pragma unroll
    for (int i = 0; i < 16; ++i) {
        int idx = i * 256 + threadIdx.x;
        int j = idx >> 6, k = idx & 63;
        o[idx] = f2bf(W[k * 64 + j]);
    }
}

__global__ __launch_bounds__(256, 3)
void ta_fused(const float* __restrict__ x, const float* __restrict__ te,
              const unsigned short* __restrict__ wT,
              const float* __restrict__ bq, const float* __restrict__ bk,
              const float* __restrict__ bv, const float* __restrict__ bo,
              const float* __restrict__ bf1, const float* __restrict__ bf2,
              float* __restrict__ out)
{
    __shared__ __align__(16) char sKb[16384];   // K [128][64] swz128 (shared, read-only after barrier)
    __shared__ __align__(16) char sVt[16384];   // V^T [64][128] swz256 (shared, read-only after barrier)
    __shared__ __align__(16) char sBn[16384];   // 4x 4KB wave-private bounce: Q -> O -> val -> h1

    const int tid  = threadIdx.x;
    const int lane = tid & 63;
    const int wv   = tid >> 6;
    const int lam  = lane & 15;
    const int g    = (lane >> 4) & 3;
    const int bid  = blockIdx.x;
    const int b    = bid / N_;
    const int n    = bid - b * N_;
    const long long base = ((long long)b * T_ * N_ + n) * F_;
    const int t0w = wv * 32;
    char* myb = sBn + wv * 4096;   // this wave's 32x64 bf16 bounce tile (local rows 0..31)

    // ---------------- P0: X = x + te straight into fragments (global, coalesced) ----------------
    short8 ax[2][2];   // [mi][kc]: lane -> row t0w+mi*16+(l&15), feats kc*32+g*8..+7
#pragma unroll
    for (int mi = 0; mi < 2; ++mi) {
        const float* xr = x  + base + (long long)(t0w + mi * 16 + lam) * ROWSTRIDE;
        const float* tr = te + base + (long long)(t0w + mi * 16 + lam) * ROWSTRIDE;
#pragma unroll
        for (int kc = 0; kc < 2; ++kc) {
            int f0 = kc * 32 + g * 8;
            float4 a0 = *(const float4*)(xr + f0);
            float4 a1 = *(const float4*)(xr + f0 + 4);
            float4 c0 = *(const float4*)(tr + f0);
            float4 c1 = *(const float4*)(tr + f0 + 4);
            U4 u;
            u.u[0] = cvtpk(a0.x + c0.x, a0.y + c0.y);
            u.u[1] = cvtpk(a0.z + c0.z, a0.w + c0.w);
            u.u[2] = cvtpk(a1.x + c1.x, a1.y + c1.y);
            u.u[3] = cvtpk(a1.z + c1.z, a1.w + c1.w);
            ax[mi][kc] = u.s;
        }
    }

    // ---------------- P1: Q,K,V projections for this wave's 32 rows ----------------
    {
#pragma unroll
        for (int w = 0; w < 3; ++w) {
            const unsigned short* wTp = wT + w * 4096;
            short8 bw[4][2];
#pragma unroll
            for (int nt = 0; nt < 4; ++nt) {
                bw[nt][0] = wfragT(wTp, nt, 0, lane);
                bw[nt][1] = wfragT(wTp, nt, 1, lane);
            }
            f32x4 acc[2][4];
#pragma unroll
            for (int mi = 0; mi < 2; ++mi)
#pragma unroll
            for (int nt = 0; nt < 4; ++nt) acc[mi][nt] = zero4();

            if (w < 2) {   // SWAPPED: D[j][t] — lane holds token t=lam, feats nt*16+g*4+r
                const float* bp = (w == 0) ? bq : bk;
                float4 bj[4];
#pragma unroll
                for (int nt = 0; nt < 4; ++nt) bj[nt] = *(const float4*)(bp + nt * 16 + g * 4);
#pragma unroll
                for (int kc = 0; kc < 2; ++kc)
#pragma unroll
                for (int mi = 0; mi < 2; ++mi)
#pragma unroll
                for (int nt = 0; nt < 4; ++nt)
                    acc[mi][nt] = __builtin_amdgcn_mfma_f32_16x16x32_bf16(bw[nt][kc], ax[mi][kc], acc[mi][nt], 0, 0, 0);
#pragma unroll
                for (int mi = 0; mi < 2; ++mi)
#pragma unroll
                for (int nt = 0; nt < 4; ++nt) {
                    unsigned d0 = cvtpk(acc[mi][nt][0] + bj[nt].x, acc[mi][nt][1] + bj[nt].y);
                    unsigned d1 = cvtpk(acc[mi][nt][2] + bj[nt].z, acc[mi][nt][3] + bj[nt].w);
                    unsigned long long pk = (unsigned long long)d0 | ((unsigned long long)d1 << 32);
                    if (w == 0) {  // Q -> bounce, local rows
                        *(unsigned long long*)(myb + swz128(mi * 16 + lam, (nt * 16 + g * 4) * 2)) = pk;
                    } else {       // K -> shared, global rows
                        *(unsigned long long*)(sKb + swz128(t0w + mi * 16 + lam, (nt * 16 + g * 4) * 2)) = pk;
                    }
                }
            } else {       // V normal: D[t][f]; pack 4 consecutive t -> V^T[f][t]
                float bias[4];
#pragma unroll
                for (int nt = 0; nt < 4; ++nt) bias[nt] = bv[nt * 16 + lam];
#pragma unroll
                for (int kc = 0; kc < 2; ++kc)
#pragma unroll
                for (int mi = 0; mi < 2; ++mi)
#pragma unroll
                for (int nt = 0; nt < 4; ++nt)
                    acc[mi][nt] = __builtin_amdgcn_mfma_f32_16x16x32_bf16(ax[mi][kc], bw[nt][kc], acc[mi][nt], 0, 0, 0);
#pragma unroll
                for (int mi = 0; mi < 2; ++mi)
#pragma unroll
                for (int nt = 0; nt < 4; ++nt) {
                    int f   = nt * 16 + lam;
                    int tb0 = t0w + mi * 16 + g * 4;
                    unsigned d0 = cvtpk(acc[mi][nt][0] + bias[nt], acc[mi][nt][1] + bias[nt]);
                    unsigned d1 = cvtpk(acc[mi][nt][2] + bias[nt], acc[mi][nt][3] + bias[nt]);
                    unsigned long long pkv = (unsigned long long)d0 | ((unsigned long long)d1 << 32);
                    *(unsigned long long*)(sVt + swz256(f, tb0 * 2)) = pkv;
                }
            }
        }
    }
    __syncthreads();   // the ONLY barrier: K and V^T now valid for all waves

    // ---------------- P2: attention, no-max softmax, 2 heads interleaved for ILP ----------------
    {
        const int tcol = lane & 31;
        const int hi4  = (lane >> 5) * 4;
#pragma unroll
        for (int hp = 0; hp < 2; ++hp) {
            const int h0 = hp * 2, h1 = hp * 2 + 1;
            short8 qf0 = ldfrag32(myb, 0, h0 * 32, lane);
            short8 qf1 = ldfrag32(myb, 0, h1 * 32, lane);
            float sum0 = 0.f, sum1 = 0.f;
            f32x4 o00 = zero4(), o01 = zero4(), o10 = zero4(), o11 = zero4();
#pragma unroll
            for (int sb = 0; sb < 4; ++sb) {
                if (sb > wv) continue;       // causal: s-tiles 0..wv (wave-uniform)
                // two independent chains in flight: loads first, then MFMAs, then VALU
                short8 kf0 = ldfrag32(sKb, sb * 32, h0 * 32, lane);
                short8 kf1 = ldfrag32(sKb, sb * 32, h1 * 32, lane);
                short8 vf0 = ldfrag16w(sVt, h0 * 16, sb * 64, lane);
                short8 vf1 = ldfrag16w(sVt, h1 * 16, sb * 64, lane);
                __builtin_amdgcn_s_setprio(1);
                f32x16 s0 = __builtin_amdgcn_mfma_f32_32x32x16_bf16(kf0, qf0, zero16(), 0, 0, 0);
                f32x16 s1 = __builtin_amdgcn_mfma_f32_32x32x16_bf16(kf1, qf1, zero16(), 0, 0, 0);
                __builtin_amdgcn_s_setprio(0);
                if (sb == wv) {              // diagonal tile mask (static index)
#pragma unroll
                    for (int r = 0; r < 16; ++r) {
                        int srow = (r & 3) + 8 * (r >> 2) + hi4;
                        if (srow > tcol) { s0[r] = -3.0e38f; s1[r] = -3.0e38f; }
                    }
                }
                U4 F00, F01, F10, F11;
                softpack(s0, sum0, F00, F01);
                softpack(s1, sum1, F10, F11);
                __builtin_amdgcn_s_setprio(1);
                o00 = __builtin_amdgcn_mfma_f32_16x16x32_bf16(vf0, F00.s, o00, 0, 0, 0);
                o01 = __builtin_amdgcn_mfma_f32_16x16x32_bf16(vf0, F01.s, o01, 0, 0, 0);
                o10 = __builtin_amdgcn_mfma_f32_16x16x32_bf16(vf1, F10.s, o10, 0, 0, 0);
                o11 = __builtin_amdgcn_mfma_f32_16x16x32_bf16(vf1, F11.s, o11, 0, 0, 0);
                __builtin_amdgcn_s_setprio(0);
            }
            sum0 += __shfl_xor(sum0, 32);
            sum1 += __shfl_xor(sum1, 32);
            float rs0 = __builtin_amdgcn_rcpf(sum0);
            float rs1 = __builtin_amdgcn_rcpf(sum1);
            // align rs to MFMA output columns: token = lam (F0-out) / lam+16 (F1-out)
            float rs00 = __shfl(rs0, lam), rs01 = __shfl(rs0, lam + 16);
            float rs10 = __shfl(rs1, lam), rs11 = __shfl(rs1, lam + 16);
            // O -> bounce (overwrites Q rows; wave-private, no barrier)
            {
                unsigned d0 = cvtpk(o00[0] * rs00, o00[1] * rs00);
                unsigned d1 = cvtpk(o00[2] * rs00, o00[3] * rs00);
                *(unsigned long long*)(myb + swz128(lam, (h0 * 16 + g * 4) * 2)) =
                    (unsigned long long)d0 | ((unsigned long long)d1 << 32);
                d0 = cvtpk(o01[0] * rs01, o01[1] * rs01);
                d1 = cvtpk(o01[2] * rs01, o01[3] * rs01);
                *(unsigned long long*)(myb + swz128(16 + lam, (h0 * 16 + g * 4) * 2)) =
                    (unsigned long long)d0 | ((unsigned long long)d1 << 32);
                d0 = cvtpk(o10[0] * rs10, o10[1] * rs10);
                d1 = cvtpk(o10[2] * rs10, o10[3] * rs10);
                *(unsigned long long*)(myb + swz128(lam, (h1 * 16 + g * 4) * 2)) =
                    (unsigned long long)d0 | ((unsigned long long)d1 << 32);
                d0 = cvtpk(o11[0] * rs11, o11[1] * rs11);
                d1 = cvtpk(o11[2] * rs11, o11[3] * rs11);
                *(unsigned long long*)(myb + swz128(16 + lam, (h1 * 16 + g * 4) * 2)) =
                    (unsigned long long)d0 | ((unsigned long long)d1 << 32);
            }
        }
    }
    // everything below is wave-private: ZERO barriers to the end

    // ---------------- P3: Wo + residual(X re-read, float4) + LN ----------------
    float val[2][4][4];
    {
        short8 af[2][2];
#pragma unroll
        for (int mi = 0; mi < 2; ++mi)
#pragma unroll
        for (int kc = 0; kc < 2; ++kc) af[mi][kc] = ldfrag16(myb, mi * 16, kc * 64, lane);
        const unsigned short* wTp = wT + 3 * 4096;
        short8 bwf[4][2]; float4 bj[4];
#pragma unroll
        for (int nt = 0; nt < 4; ++nt) {
            bwf[nt][0] = wfragT(wTp, nt, 0, lane);
            bwf[nt][1] = wfragT(wTp, nt, 1, lane);
            bj[nt]     = *(const float4*)(bo + nt * 16 + g * 4);
        }
        f32x4 acc[2][4];
#pragma unroll
        for (int mi = 0; mi < 2; ++mi)
#pragma unroll
        for (int nt = 0; nt < 4; ++nt) acc[mi][nt] = zero4();
#pragma unroll
        for (int kc = 0; kc < 2; ++kc)
#pragma unroll
        for (int mi = 0; mi < 2; ++mi)
#pragma unroll
        for (int nt = 0; nt < 4; ++nt)
            acc[mi][nt] = __builtin_amdgcn_mfma_f32_16x16x32_bf16(bwf[nt][kc], af[mi][kc], acc[mi][nt], 0, 0, 0);
#pragma unroll
        for (int mi = 0; mi < 2; ++mi)
#pragma unroll
        for (int nt = 0; nt < 4; ++nt) {
            long long roff = base + (long long)(t0w + mi * 16 + lam) * ROWSTRIDE + nt * 16 + g * 4;
            float4 xv = *(const float4*)(x + roff);
            float4 tv = *(const float4*)(te + roff);
            val[mi][nt][0] = acc[mi][nt][0] + bj[nt].x + xv.x + tv.x;
            val[mi][nt][1] = acc[mi][nt][1] + bj[nt].y + xv.y + tv.y;
            val[mi][nt][2] = acc[mi][nt][2] + bj[nt].z + xv.z + tv.z;
            val[mi][nt][3] = acc[mi][nt][3] + bj[nt].w + xv.w + tv.w;
        }
        lnS(val);
#pragma unroll
        for (int mi = 0; mi < 2; ++mi)
#pragma unroll
        for (int nt = 0; nt < 4; ++nt) {
            unsigned d0 = cvtpk(val[mi][nt][0], val[mi][nt][1]);
            unsigned d1 = cvtpk(val[mi][nt][2], val[mi][nt][3]);
            unsigned long long pk = (unsigned long long)d0 | ((unsigned long long)d1 << 32);
            *(unsigned long long*)(myb + swz128(mi * 16 + lam, (nt * 16 + g * 4) * 2)) = pk;
        }
    }

    // ---------------- P4: FF1 + ReLU ----------------
    {
        short8 af[2][2];
#pragma unroll
        for (int mi = 0; mi < 2; ++mi)
#pragma unroll
        for (int kc = 0; kc < 2; ++kc) af[mi][kc] = ldfrag16(myb, mi * 16, kc * 64, lane);
        const unsigned short* wTp = wT + 4 * 4096;
        short8 bwf[4][2]; float4 bj[4];
#pragma unroll
        for (int nt = 0; nt < 4; ++nt) {
            bwf[nt][0] = wfragT(wTp, nt, 0, lane);
            bwf[nt][1] = wfragT(wTp, nt, 1, lane);
            bj[nt]     = *(const float4*)(bf1 + nt * 16 + g * 4);
        }
        f32x4 acc[2][4];
#pragma unroll
        for (int mi = 0; mi < 2; ++mi)
#pragma unroll
        for (int nt = 0; nt < 4; ++nt) acc[mi][nt] = zero4();
#pragma unroll
        for (int kc = 0; kc < 2; ++kc)
#pragma unroll
        for (int mi = 0; mi < 2; ++mi)
#pragma unroll
        for (int nt = 0; nt < 4; ++nt)
            acc[mi][nt] = __builtin_amdgcn_mfma_f32_16x16x32_bf16(bwf[nt][kc], af[mi][kc], acc[mi][nt], 0, 0, 0);
#pragma unroll
        for (int mi = 0; mi < 2; ++mi)
#pragma unroll
        for (int nt = 0; nt < 4; ++nt) {
            unsigned d0 = cvtpk(fmaxf(acc[mi][nt][0] + bj[nt].x, 0.f), fmaxf(acc[mi][nt][1] + bj[nt].y, 0.f));
            unsigned d1 = cvtpk(fmaxf(acc[mi][nt][2] + bj[nt].z, 0.f), fmaxf(acc[mi][nt][3] + bj[nt].w, 0.f));
            unsigned long long pk = (unsigned long long)d0 | ((unsigned long long)d1 << 32);
            *(unsigned long long*)(myb + swz128(mi * 16 + lam, (nt * 16 + g * 4) * 2)) = pk;
        }
    }

    // ---------------- P5: FF2 + residual + LN + float4 store ----------------
    {
        short8 af[2][2];
#pragma unroll
        for (int mi = 0; mi < 2; ++mi)
#pragma unroll
        for (int kc = 0; kc < 2; ++kc) af[mi][kc] = ldfrag16(myb, mi * 16, kc * 64, lane);
        const unsigned short* wTp = wT + 5 * 4096;
        short8 bwf[4][2]; float4 bj[4];
#pragma unroll
        for (int nt = 0; nt < 4; ++nt) {
            bwf[nt][0] = wfragT(wTp, nt, 0, lane);
            bwf[nt][1] = wfragT(wTp, nt, 1, lane);
            bj[nt]     = *(const float4*)(bf2 + nt * 16 + g * 4);
        }
        f32x4 acc[2][4];
#pragma unroll
        for (int mi = 0; mi < 2; ++mi)
#pragma unroll
        for (int nt = 0; nt < 4; ++nt) acc[mi][nt] = zero4();
#pragma unroll
        for (int kc = 0; kc < 2; ++kc)
#pragma unroll
        for (int mi = 0; mi < 2; ++mi)
#pragma unroll
        for (int nt = 0; nt < 4; ++nt)
            acc[mi][nt] = __builtin_amdgcn_mfma_f32_16x16x32_bf16(bwf[nt][kc], af[mi][kc], acc[mi][nt], 0, 0, 0);
        float z[2][4][4];
#pragma unroll
        for (int mi = 0; mi < 2; ++mi)
#pragma unroll
        for (int nt = 0; nt < 4; ++nt) {
            z[mi][nt][0] = acc[mi][nt][0] + bj[nt].x + val[mi][nt][0];
            z[mi][nt][1] = acc[mi][nt][1] + bj[nt].y + val[mi][nt][1];
            z[mi][nt][2] = acc[mi][nt][2] + bj[nt].z + val[mi][nt][2];
            z[mi][nt][3] = acc[mi][nt][3] + bj[nt].w + val[mi][nt][3];
        }
        lnS(z);
#pragma unroll
        for (int mi = 0; mi < 2; ++mi)
#pragma unroll
        for (int nt = 0; nt < 4; ++nt) {
            float4 o = {z[mi][nt][0], z[mi][nt][1], z[mi][nt][2], z[mi][nt][3]};
            *(float4*)(out + base + (long long)(t0w + mi * 16 + lam) * ROWSTRIDE + nt * 16 + g * 4) = o;
        }
    }
}

extern "C" void kernel_launch(void* const* d_in, const int* in_sizes, int n_in,
                              void* d_out, int out_size, void* d_ws, size_t ws_size,
                              hipStream_t stream) {
    const float* x   = (const float*)d_in[0];
    const float* te  = (const float*)d_in[1];
    const float* Wq  = (const float*)d_in[2];
    const float* bq  = (const float*)d_in[3];
    const float* Wk  = (const float*)d_in[4];
    const float* bk  = (const float*)d_in[5];
    const float* Wv  = (const float*)d_in[6];
    const float* bv  = (const float*)d_in[7];
    const float* Wo  = (const float*)d_in[8];
    const float* bo  = (const float*)d_in[9];
    const float* Wf1 = (const float*)d_in[10];
    const float* bf1 = (const float*)d_in[11];
    const float* Wf2 = (const float*)d_in[12];
    const float* bf2 = (const float*)d_in[13];
    unsigned short* wsT = (unsigned short*)d_ws;

    prep_weights<<<dim3(6), dim3(256), 0, stream>>>(Wq, Wk, Wv, Wo, Wf1, Wf2, wsT);
    ta_fused<<<dim3(B_ * N_), dim3(256), 0, stream>>>(
        x, te, wsT, bq, bk, bv, bo, bf1, bf2, (float*)d_out);
}